// Round 14
// baseline (4352.322 us; speedup 1.0000x reference)
//
#include <hip/hip_runtime.h>
#include <hip/hip_bf16.h>
#include <math.h>

// Tx=48 Ty=48 Bn=64 DW=512 E=512 D=1024 A=512 VS=VT=32000
typedef __attribute__((ext_vector_type(8))) short bf16x8;
typedef __attribute__((ext_vector_type(4))) short bf16x4;
typedef __attribute__((ext_vector_type(4))) float f32x4;
typedef unsigned short u16;
typedef unsigned int u32;

__device__ __forceinline__ float bf2f(u16 u) {
    union { float f; u32 i; } v; v.i = ((u32)u) << 16; return v.f;
}
__device__ __forceinline__ float bflo(u32 v) {
    union { float f; u32 u; } x; x.u = v << 16; return x.f;
}
__device__ __forceinline__ float bfhi(u32 v) {
    union { float f; u32 u; } x; x.u = v & 0xFFFF0000u; return x.f;
}
__device__ __forceinline__ u16 f2bf(float x) {
    union { float f; u32 u; } v; v.f = x;
    u32 r = v.u + 0x7FFF + ((v.u >> 16) & 1);
    return (u16)(r >> 16);
}
__device__ __forceinline__ u32 f2bf2(float a, float b) {
    return (u32)f2bf(a) | ((u32)f2bf(b) << 16);
}
__device__ __forceinline__ float sigf(float x) { return 1.0f / (1.0f + expf(-x)); }

// Write-through stores to the memory-side (L3) coherence point.
__device__ __forceinline__ void st_wt_u16(u16* p, u16 v) {
    asm volatile("global_store_short %0, %1, off sc0 sc1" :: "v"(p), "v"((u32)v) : "memory");
}
__device__ __forceinline__ void st_wt_f32(float* p, float v) {
    asm volatile("global_store_dword %0, %1, off sc0 sc1" :: "v"(p), "v"(v) : "memory");
}
__device__ __forceinline__ void st_wt_u32(u32* p, u32 v) {
    asm volatile("global_store_dword %0, %1, off sc0 sc1" :: "v"(p), "v"(v) : "memory");
}

// Hierarchical barrier: each block wt-stores its own flag (64B-strided line).
// Aggregator block polls ALL flags; broadcasts ph to replicated go-lines;
// every other block polls only its own replica.
__device__ __forceinline__ void gbarH(u32* flags, u32* go, int myidx, int aggbid,
                                      u32 ph, int nblk, int nrepmask) {
    __syncthreads();
    if ((int)blockIdx.x == aggbid) {
        if (threadIdx.x == 0) st_wt_u32(flags + (size_t)myidx * 16, ph);
        if (threadIdx.x < 64) {
            bool ok = false;
            if (nblk == 256) {
                const u32* p = flags + (size_t)threadIdx.x * 64;
                while (!ok) {
                    u32 a, b, c, d;
                    asm volatile(
                        "global_load_dword %0, %4, off sc0 sc1\n\t"
                        "global_load_dword %1, %5, off sc0 sc1\n\t"
                        "global_load_dword %2, %6, off sc0 sc1\n\t"
                        "global_load_dword %3, %7, off sc0 sc1\n\t"
                        "s_waitcnt vmcnt(0)"
                        : "=&v"(a), "=&v"(b), "=&v"(c), "=&v"(d)
                        : "v"(p), "v"(p + 16), "v"(p + 32), "v"(p + 48)
                        : "memory");
                    ok = __all((a >= ph) && (b >= ph) && (c >= ph) && (d >= ph));
                    if (!ok) __builtin_amdgcn_s_sleep(2);
                }
            } else {
                const u32* p = flags + (size_t)threadIdx.x * 16;
                while (!ok) {
                    u32 a;
                    asm volatile("global_load_dword %0, %1, off sc0 sc1\n\ts_waitcnt vmcnt(0)"
                                 : "=&v"(a) : "v"(p) : "memory");
                    ok = __all(a >= ph);
                    if (!ok) __builtin_amdgcn_s_sleep(2);
                }
            }
            if ((int)threadIdx.x <= nrepmask)
                st_wt_u32(go + (size_t)threadIdx.x * 16, ph);
        }
        __syncthreads();
    } else {
        if (threadIdx.x == 0) {
            st_wt_u32(flags + (size_t)myidx * 16, ph);
            const u32* gp = go + (size_t)(myidx & nrepmask) * 16;
            u32 v;
            do {
                asm volatile("global_load_dword %0, %1, off sc0 sc1\n\ts_waitcnt vmcnt(0)"
                             : "=&v"(v) : "v"(gp) : "memory");
                if (v < ph) __builtin_amdgcn_s_sleep(1);
            } while (v < ph);
        }
        __syncthreads();
    }
}

// ---------------------------------------------------------------------------
// MFMA GEMM (batched ops): C = act(A@B^T + bias + Cin), 64x64 tile.
// ---------------------------------------------------------------------------
template<int OUTBF, int ACT, int CIN>
__global__ __launch_bounds__(256) void mgemm(
    const u16* __restrict__ A, int lda,
    const u16* __restrict__ B, int ldb,
    const float* __restrict__ bias,
    const u16* __restrict__ Cin,
    void* __restrict__ Cout,
    int N, int K,
    const u16* A2, const u16* B2, const float* bias2, const u16* Cin2, void* Cout2)
{
    if (blockIdx.z == 1) { A = A2; B = B2; bias = bias2; Cin = Cin2; Cout = Cout2; }
    const int lane = threadIdx.x & 63;
    const int wave = threadIdx.x >> 6;
    const int wm = wave >> 1, wn = wave & 1;
    const int lr = lane & 15, lg = lane >> 4;
    const size_t bm = (size_t)blockIdx.y * 64, bn = (size_t)blockIdx.x * 64;
    const u16* Ap = A + (bm + wm * 32 + lr) * (size_t)lda + lg * 8;
    const u16* Bp = B + (bn + wn * 32 + lr) * (size_t)ldb + lg * 8;
    f32x4 acc[2][2] = {};
    for (int k0 = 0; k0 < K; k0 += 32) {
        bf16x8 a0 = *(const bf16x8*)(Ap + k0);
        bf16x8 a1 = *(const bf16x8*)(Ap + k0 + 16 * (size_t)lda);
        bf16x8 b0 = *(const bf16x8*)(Bp + k0);
        bf16x8 b1 = *(const bf16x8*)(Bp + k0 + 16 * (size_t)ldb);
        acc[0][0] = __builtin_amdgcn_mfma_f32_16x16x32_bf16(a0, b0, acc[0][0], 0, 0, 0);
        acc[0][1] = __builtin_amdgcn_mfma_f32_16x16x32_bf16(a0, b1, acc[0][1], 0, 0, 0);
        acc[1][0] = __builtin_amdgcn_mfma_f32_16x16x32_bf16(a1, b0, acc[1][0], 0, 0, 0);
        acc[1][1] = __builtin_amdgcn_mfma_f32_16x16x32_bf16(a1, b1, acc[1][1], 0, 0, 0);
    }
    #pragma unroll
    for (int fi = 0; fi < 2; ++fi)
    #pragma unroll
    for (int fj = 0; fj < 2; ++fj) {
        size_t col = bn + wn * 32 + fj * 16 + lr;
        float bv = bias ? bias[col] : 0.0f;
        #pragma unroll
        for (int r = 0; r < 4; ++r) {
            size_t row = bm + wm * 32 + fi * 16 + lg * 4 + r;
            float v = acc[fi][fj][r] + bv;
            if constexpr (CIN) v += bf2f(Cin[row * (size_t)N + col]);
            if constexpr (ACT) v = tanhf(v);
            if constexpr (OUTBF) ((u16*)Cout)[row * (size_t)N + col] = f2bf(v);
            else                 ((float*)Cout)[row * (size_t)N + col] = v;
        }
    }
}

// ---------------------------------------------------------------------------
// Persistent encoder (unchanged from R13): 128 blocks, 1 bar/step.
// ---------------------------------------------------------------------------
__global__ __launch_bounds__(256, 1) void enc_persist(
    const u16* __restrict__ WhhFg, const u16* __restrict__ WhhRg,
    const u16* __restrict__ preAF, const u16* __restrict__ preAR,
    const float* __restrict__ bF, const float* __restrict__ bR,
    const float* __restrict__ xm,
    u16* hAbuf, u16* hBbuf,
    u16* __restrict__ ctxB, u32* encSync)
{
    const int tid = threadIdx.x, bid = blockIdx.x;
    const int lane = tid & 63, wave = tid >> 6;
    const int lr = lane & 15, lg = lane >> 4;
    const int dir = bid >> 6;
    const int nb = bid & 63;
    const u16* Whh = dir ? WhhRg : WhhFg;
    const u16* preA = dir ? preAR : preAF;
    const float* bias = dir ? bR : bF;
    u16* hbase = dir ? hBbuf : hAbuf;
    u32* flags = encSync + (size_t)dir * 1280;
    u32* go = flags + 1024;
    const int aggbid = dir * 64;
    __shared__ u16 whh[32 * 520];
    __shared__ float zs[64 * 33];
    for (int i = tid; i < 32 * 64; i += 256) {
        int r = i >> 6, c = (i & 63) * 8;
        *(bf16x8*)&whh[r * 520 + c] = *(const bf16x8*)&Whh[(size_t)(nb * 32 + r) * 512 + c];
    }
    __syncthreads();
    const int gb = tid & 63, dl0 = tid >> 6;
    float creg[2] = {0.f, 0.f};
    u32 ph = 0;
    for (int s = 0; s < 48; ++s) {
        const int t = dir ? (47 - s) : s;
        if (s > 0) {
            const u16* hc = hbase + (size_t)s * 32768;
            const u16* Ap = hc + (wave * 16 + lr) * 512 + lg * 8;
            f32x4 acc0 = {}, acc1 = {};
            #pragma unroll 4
            for (int k0 = 0; k0 < 512; k0 += 32) {
                bf16x8 a  = *(const bf16x8*)(Ap + k0);
                bf16x8 b0 = *(const bf16x8*)&whh[lr * 520 + k0 + lg * 8];
                bf16x8 b1 = *(const bf16x8*)&whh[(16 + lr) * 520 + k0 + lg * 8];
                acc0 = __builtin_amdgcn_mfma_f32_16x16x32_bf16(a, b0, acc0, 0, 0, 0);
                acc1 = __builtin_amdgcn_mfma_f32_16x16x32_bf16(a, b1, acc1, 0, 0, 0);
            }
            #pragma unroll
            for (int r = 0; r < 4; ++r) {
                int row = wave * 16 + lg * 4 + r;
                zs[row * 33 + lr] = acc0[r];
                zs[row * 33 + 16 + lr] = acc1[r];
            }
            __syncthreads();
        }
        u16* hnx = hbase + (size_t)(s + 1) * 32768;
        #pragma unroll
        for (int q = 0; q < 2; ++q) {
            int dl = dl0 + q * 4;
            int dg = nb * 8 + dl;
            bf16x4 pa = *(const bf16x4*)&preA[((size_t)t * 64 + gb) * 2048 + nb * 32 + 4 * dl];
            float iv = bf2f((u16)pa[0]) + bias[dg];
            float fv = bf2f((u16)pa[1]) + bias[512 + dg];
            float gv = bf2f((u16)pa[2]) + bias[1024 + dg];
            float ov = bf2f((u16)pa[3]) + bias[1536 + dg];
            if (s > 0) {
                iv += zs[gb * 33 + 4 * dl + 0];
                fv += zs[gb * 33 + 4 * dl + 1];
                gv += zs[gb * 33 + 4 * dl + 2];
                ov += zs[gb * 33 + 4 * dl + 3];
            }
            float cn = sigf(fv) * creg[q] + sigf(iv) * tanhf(gv);
            float hn = sigf(ov) * tanhf(cn);
            creg[q] = cn;
            st_wt_u16(&hnx[gb * 512 + dg], f2bf(hn));
            ctxB[((size_t)t * 64 + gb) * 1024 + dir * 512 + dg] = f2bf(hn * xm[t * 64 + gb]);
        }
        if (s < 47) gbarH(flags, go, nb, aggbid, ++ph, 64, 15);
    }
}

// ---------------------------------------------------------------------------
// Persistent decoder: 256 blocks x 512 threads, 2 barriers/step.
// att blocks (0..127, pair per batch row): hold G rows for OWN b in 96 VGPRs;
//   AZ phase = scores+softmax (alpha stays in LDS) + ctx_t + z=alpha.G(reg)
//   + zpart(float4 read) + gates -> ht.
// upper blocks (128..255): SVZ phase zpart MFMA (32-col Wz strip in LDS).
// All blocks: SVZ sv GEMV (2 W1h rows each, MLP-batched).
// ---------------------------------------------------------------------------
__global__ __launch_bounds__(512, 1) void dec_persist(
    const u16* __restrict__ WzB, const u16* __restrict__ W1hB,
    const u16* __restrict__ attctxB, const u16* __restrict__ ctxB,
    const u16* __restrict__ preYB, const u16* __restrict__ yembB,
    const float* __restrict__ att2W, const float* __restrict__ att2b,
    const float* __restrict__ xmask, const float* __restrict__ cellb,
    u16* htR, const float* __restrict__ ctF,
    float* svB, float* zpartR, const u16* __restrict__ G,
    u16* c3r, u32* decFlags, u32* decGo)
{
    const int tid = threadIdx.x, bid = blockIdx.x;
    const int lane = tid & 63, wave = tid >> 6;
    const int lr = lane & 15, lg = lane >> 4;
    __shared__ u16 wzl[32 * 1544];    // upper: Wz strip; att: big[48*512] aliases
    __shared__ u16 w1h[2 * 1024];
    __shared__ float svzs[4 * 2080];  // sv transpose scratch (4 waves x 32x65)
    __shared__ float a2s[64];
    u16* big = wzl;                   // att alias: 48*512 = 24576 u16 <= 49408

    const int isatt = (bid < 128);
    const int ab = bid >> 1;
    const int eh = bid & 1;
    const int u = bid - 128;
    const int su = ((u & 7) << 4) | (u >> 3);   // bijective strip 0..127
    const int scol0 = su * 32;

    // ---- one-time staging ----
    for (int i = tid; i < 256; i += 512) {
        int r = i >> 7, c = (i & 127) * 8;
        *(bf16x8*)&w1h[r * 1024 + c] = *(const bf16x8*)&W1hB[(size_t)(bid * 2 + r) * 1024 + c];
    }
    if (isatt) {
        for (int i = tid; i < 48 * 64; i += 512) {
            int tp = i >> 6, c = (i & 63) * 8;
            *(bf16x8*)&big[tp * 512 + c] =
                *(const bf16x8*)&attctxB[((size_t)tp * 64 + ab) * 512 + c];
        }
    } else {
        for (int i = tid; i < 32 * 192; i += 512) {
            int r = i / 192, c = (i % 192) * 8;
            *(bf16x8*)&wzl[r * 1544 + c] =
                *(const bf16x8*)&WzB[(size_t)(scol0 + r) * 2560 + 1024 + c];
        }
    }
    float a2wreg[8];
    float xmr = 0.f;
    uint2 gfrag[48];
    float cb_reg[4];
    float ct_reg = 0.f;
    const int d = eh * 512 + tid;        // this thread's gate-group (att role)
    const int n0 = 4 * d;                // z cols n0..n0+3
    if (isatt) {
        #pragma unroll
        for (int k = 0; k < 8; ++k) a2wreg[k] = att2W[k * 64 + lane];
        if (tid < 64) xmr = xmask[tid * 64 + ab];
        #pragma unroll
        for (int tp = 0; tp < 48; ++tp)
            gfrag[tp] = *(const uint2*)&G[((size_t)tp * 64 + ab) * 4096 + n0];
        #pragma unroll
        for (int g = 0; g < 4; ++g) cb_reg[g] = cellb[g * 1024 + d];
        ct_reg = ctF[ab * 1024 + d];
    }
    __syncthreads();
    const float att2b0 = att2b[0];

    // SVZ: sv GEMV (waves 0-3, all blocks) || zpart MFMA (waves 4-7, upper)
    auto svz_phase = [&](int tt) {
        const u16* htT = htR + (size_t)tt * 65536;
        if (wave < 4) {
            const int jl = wave & 1;
            const int bh = wave >> 1;
            const int j = bid * 2 + jl;
            float* svT = svB + (size_t)tt * 32768;
            bf16x8 wv0 = *(const bf16x8*)&w1h[jl * 1024 + lane * 8];
            bf16x8 wv1 = *(const bf16x8*)&w1h[jl * 1024 + 512 + lane * 8];
            float s[32];
            #pragma unroll 8
            for (int bi = 0; bi < 32; ++bi) {
                const u16* hp = htT + (bh * 32 + bi) * 1024 + lane * 8;
                bf16x8 h0 = *(const bf16x8*)(hp);
                bf16x8 h1 = *(const bf16x8*)(hp + 512);
                float a = 0.f;
                #pragma unroll
                for (int q = 0; q < 8; ++q)
                    a += bf2f((u16)h0[q]) * bf2f((u16)wv0[q])
                       + bf2f((u16)h1[q]) * bf2f((u16)wv1[q]);
                s[bi] = a;
            }
            float* zone = svzs + wave * 2080;
            #pragma unroll 8
            for (int bi = 0; bi < 32; ++bi) zone[bi * 65 + lane] = s[bi];
            if (lane < 32) {
                const float* zr = zone + lane * 65;
                float tsum = 0.f;
                #pragma unroll
                for (int q = 0; q < 64; ++q) tsum += zr[q];
                int b = bh * 32 + lane;
                st_wt_f32(&svT[b * 512 + j],
                          tsum + bf2f(preYB[((size_t)tt * 64 + b) * 512 + j]));
            }
        } else if (!isatt) {
            const int bt = wave - 4;    // b-tile 0..3
            const u16* Ah = htT + (bt * 16 + lr) * 1024 + lg * 8;
            const u16* Ay = yembB + ((size_t)tt * 64 + bt * 16 + lr) * 512 + lg * 8;
            f32x4 acc0 = {}, acc1 = {};
            #pragma unroll 4
            for (int k0 = 0; k0 < 1024; k0 += 32) {
                bf16x8 a = *(const bf16x8*)(Ah + k0);
                bf16x8 b0 = *(const bf16x8*)&wzl[lr * 1544 + k0 + lg * 8];
                bf16x8 b1 = *(const bf16x8*)&wzl[(16 + lr) * 1544 + k0 + lg * 8];
                acc0 = __builtin_amdgcn_mfma_f32_16x16x32_bf16(a, b0, acc0, 0, 0, 0);
                acc1 = __builtin_amdgcn_mfma_f32_16x16x32_bf16(a, b1, acc1, 0, 0, 0);
            }
            #pragma unroll 4
            for (int k0 = 0; k0 < 512; k0 += 32) {
                bf16x8 a = *(const bf16x8*)(Ay + k0);
                bf16x8 b0 = *(const bf16x8*)&wzl[lr * 1544 + 1024 + k0 + lg * 8];
                bf16x8 b1 = *(const bf16x8*)&wzl[(16 + lr) * 1544 + 1024 + k0 + lg * 8];
                acc0 = __builtin_amdgcn_mfma_f32_16x16x32_bf16(a, b0, acc0, 0, 0, 0);
                acc1 = __builtin_amdgcn_mfma_f32_16x16x32_bf16(a, b1, acc1, 0, 0, 0);
            }
            float* zpT = zpartR + (size_t)tt * 262144;
            #pragma unroll
            for (int r = 0; r < 4; ++r) {
                int b = bt * 16 + lg * 4 + r;
                st_wt_f32(&zpT[(size_t)b * 4096 + scol0 + lr], acc0[r]);
                st_wt_f32(&zpT[(size_t)b * 4096 + scol0 + 16 + lr], acc1[r]);
            }
        }
    };

    u32 ph = 0;
    svz_phase(0);
    gbarH(decFlags, decGo, bid, 255, ++ph, 256, 31);

    for (int t = 0; t < 48; ++t) {
        // ================= AZ phase (att blocks; upper idle) =================
        if (isatt) {
            const float* svT = svB + (size_t)t * 32768;
            float svr[8];
            #pragma unroll
            for (int k = 0; k < 8; ++k) svr[k] = svT[ab * 512 + k * 64 + lane];
            for (int tp = wave; tp < 48; tp += 8) {
                float s = 0.f;
                #pragma unroll
                for (int k = 0; k < 8; ++k)
                    s += a2wreg[k] * tanhf(bf2f(big[tp * 512 + k * 64 + lane]) + svr[k]);
                #pragma unroll
                for (int m = 32; m; m >>= 1) s += __shfl_xor(s, m);
                if (lane == 0) a2s[tp] = s + att2b0;
            }
            __syncthreads();
            if (tid < 64) {
                float v = (tid < 48) ? a2s[tid] : -1e30f;
                float m = v;
                #pragma unroll
                for (int sh = 32; sh; sh >>= 1) m = fmaxf(m, __shfl_xor(m, sh));
                float e = (tid < 48) ? expf(v - m) * xmr : 0.f;
                float ssum = e;
                #pragma unroll
                for (int sh = 32; sh; sh >>= 1) ssum += __shfl_xor(ssum, sh);
                if (tid < 48) a2s[tid] = e / (ssum + 1e-15f);
            }
            __syncthreads();
            u16* c3rt = c3r + (size_t)t * 64 * 2560 + (size_t)ab * 2560;
            if (tid < 256) {
                float c0 = 0.f, c1 = 0.f;
                #pragma unroll
                for (int tp = 0; tp < 48; ++tp) {
                    float al = a2s[tp];
                    u32 cv = *(const u32*)&ctxB[((size_t)tp * 64 + ab) * 1024 + eh * 512 + 2 * tid];
                    c0 += al * bflo(cv); c1 += al * bfhi(cv);
                }
                *(u32*)&c3rt[eh * 512 + 2 * tid] = f2bf2(c0, c1);
            } else if (tid < 384) {
                int i = tid - 256;
                *(u32*)&c3rt[2048 + eh * 256 + 2 * i] =
                    *(const u32*)&yembB[((size_t)t * 64 + ab) * 512 + eh * 256 + 2 * i];
            }
            // z = alpha.Gfrag + zpart + bias -> gates -> ht
            float4 zp4 = *(const float4*)&zpartR[(size_t)t * 262144 + (size_t)ab * 4096 + n0];
            float zv0 = cb_reg[0] + zp4.x;
            float zv1 = cb_reg[1] + zp4.y;
            float zv2 = cb_reg[2] + zp4.z;
            float zv3 = cb_reg[3] + zp4.w;
            #pragma unroll
            for (int tp = 0; tp < 48; ++tp) {
                float al = a2s[tp];
                uint2 g2 = gfrag[tp];
                zv0 += al * bflo(g2.x); zv1 += al * bfhi(g2.x);
                zv2 += al * bflo(g2.y); zv3 += al * bfhi(g2.y);
            }
            float cn = sigf(zv1) * ct_reg + sigf(zv0) * tanhf(zv2);
            float hn = sigf(zv3) * tanhf(cn);
            ct_reg = cn;
            u16 hb = f2bf(hn);
            st_wt_u16(&htR[(size_t)(t + 1) * 65536 + ab * 1024 + d], hb);
            c3rt[1024 + d] = hb;
        }
        if (t < 47) {
            gbarH(decFlags, decGo, bid, 255, ++ph, 256, 31);
            svz_phase(t + 1);
            gbarH(decFlags, decGo, bid, 255, ++ph, 256, 31);
        }
    }
}

// ---------------------------------------------------------------------------
// Fused logits GEMM + partial log-softmax. Grid (48, 500).
// ---------------------------------------------------------------------------
__global__ __launch_bounds__(256) void logits_lsm(
    const u16* __restrict__ A, const u16* __restrict__ B,
    const float* __restrict__ outb, const int* __restrict__ ydata,
    float2* __restrict__ part, float* __restrict__ logy)
{
    const int lane = threadIdx.x & 63;
    const int wave = threadIdx.x >> 6;
    const int wm = wave >> 1, wn = wave & 1;
    const int lr = lane & 15, lg = lane >> 4;
    const size_t bm = (size_t)blockIdx.x * 64, bn = (size_t)blockIdx.y * 64;
    const u16* Ap = A + (bm + wm * 32 + lr) * 512 + lg * 8;
    const u16* Bp = B + (bn + wn * 32 + lr) * 512 + lg * 8;
    f32x4 acc[2][2] = {};
    for (int k0 = 0; k0 < 512; k0 += 32) {
        bf16x8 a0 = *(const bf16x8*)(Ap + k0);
        bf16x8 a1 = *(const bf16x8*)(Ap + k0 + 16 * 512);
        bf16x8 b0 = *(const bf16x8*)(Bp + k0);
        bf16x8 b1 = *(const bf16x8*)(Bp + k0 + 16 * 512);
        acc[0][0] = __builtin_amdgcn_mfma_f32_16x16x32_bf16(a0, b0, acc[0][0], 0, 0, 0);
        acc[0][1] = __builtin_amdgcn_mfma_f32_16x16x32_bf16(a0, b1, acc[0][1], 0, 0, 0);
        acc[1][0] = __builtin_amdgcn_mfma_f32_16x16x32_bf16(a1, b0, acc[1][0], 0, 0, 0);
        acc[1][1] = __builtin_amdgcn_mfma_f32_16x16x32_bf16(a1, b1, acc[1][1], 0, 0, 0);
    }
    __shared__ float sm[64][2];
    __shared__ float ss[64][2];
    const float b0 = outb[bn + wn * 32 + lr];
    const float b1 = outb[bn + wn * 32 + 16 + lr];
    #pragma unroll
    for (int fi = 0; fi < 2; ++fi) {
        #pragma unroll
        for (int r = 0; r < 4; ++r) {
            int rloc = wm * 32 + fi * 16 + lg * 4 + r;
            size_t row = bm + rloc;
            float v0 = acc[fi][0][r] + b0;
            float v1 = acc[fi][1][r] + b1;
            int yt = ydata[row];
            if (yt == (int)(bn + wn * 32 + lr))      logy[row] = v0;
            if (yt == (int)(bn + wn * 32 + 16 + lr)) logy[row] = v1;
            float m = fmaxf(v0, v1);
            #pragma unroll
            for (int sh = 1; sh < 16; sh <<= 1) m = fmaxf(m, __shfl_xor(m, sh));
            float s = expf(v0 - m) + expf(v1 - m);
            #pragma unroll
            for (int sh = 1; sh < 16; sh <<= 1) s += __shfl_xor(s, sh);
            if (lr == 0) { sm[rloc][wn] = m; ss[rloc][wn] = s; }
        }
    }
    __syncthreads();
    if (threadIdx.x < 64) {
        float m0 = sm[threadIdx.x][0], m1 = sm[threadIdx.x][1];
        float m = fmaxf(m0, m1);
        float s = ss[threadIdx.x][0] * expf(m0 - m) + ss[threadIdx.x][1] * expf(m1 - m);
        part[(bm + threadIdx.x) * 500 + blockIdx.y] = make_float2(m, s);
    }
}

__global__ __launch_bounds__(64) void lsm_reduce(
    const float2* __restrict__ part, const float* __restrict__ logy,
    const float* __restrict__ ymask, float* __restrict__ lossb)
{
    int r = blockIdx.x, lane = threadIdx.x;
    float m = -1e30f;
    for (int i = lane; i < 500; i += 64) m = fmaxf(m, part[(size_t)r * 500 + i].x);
    #pragma unroll
    for (int sh = 32; sh; sh >>= 1) m = fmaxf(m, __shfl_xor(m, sh));
    float s = 0.f;
    for (int i = lane; i < 500; i += 64) {
        float2 p = part[(size_t)r * 500 + i];
        s += p.y * expf(p.x - m);
    }
    #pragma unroll
    for (int sh = 32; sh; sh >>= 1) s += __shfl_xor(s, sh);
    if (lane == 0) {
        float lp = logy[r] - m - logf(s);
        lossb[r] = -lp * ymask[r] * (1.0f / 64.0f);
    }
}

// ---------------------------------------------------------------------------
// Small kernels
// ---------------------------------------------------------------------------
__global__ void convb(const float* __restrict__ src, int sld, int K,
                      u16* __restrict__ dst, int total)
{
    int idx = blockIdx.x * 256 + threadIdx.x;
    if (idx >= total) return;
    int n = idx / K, k = idx - n * K;
    dst[idx] = f2bf(src[(size_t)n * sld + k]);
}

__global__ void conv_gate4(const float* __restrict__ src, u16* __restrict__ dst,
                           int H, int K, int total)
{
    int idx = blockIdx.x * 256 + threadIdx.x;
    if (idx >= total) return;
    int n = idx / K, k = idx - n * K;
    int d = n >> 2, g = n & 3;
    dst[idx] = f2bf(src[(size_t)(g * H + d) * K + k]);
}

__global__ void build_wz_g4(const float* __restrict__ Wih, const float* __restrict__ Whh,
                            u16* __restrict__ Wz)
{
    int idx = blockIdx.x * 256 + threadIdx.x;  // 4096*2560
    int j = idx % 2560, np = idx / 2560;
    int n = (np & 3) * 1024 + (np >> 2);
    float v;
    if (j < 1024)      v = Wih[(size_t)n * 1536 + 512 + j];
    else if (j < 2048) v = Whh[(size_t)n * 1024 + (j - 1024)];
    else               v = Wih[(size_t)n * 1536 + (j - 2048)];
    Wz[idx] = f2bf(v);
}

__global__ void embed_kernel(const int* __restrict__ xd, const float* __restrict__ xm,
                             const int* __restrict__ yd,
                             const float* __restrict__ src_emb, const float* __restrict__ dec_emb,
                             u16* __restrict__ x_emb, u16* __restrict__ y_emb)
{
    int idx = blockIdx.x * 256 + threadIdx.x;   // 48*64*512
    int d = idx & 511;
    int tb = idx >> 9;
    if (blockIdx.y == 0) {
        int v = xd[tb];
        x_emb[idx] = f2bf(src_emb[(size_t)v * 512 + d] * xm[tb]);
    } else {
        int t = tb >> 6, b = tb & 63;
        int v = (t == 0) ? 0 : yd[(t - 1) * 64 + b];
        y_emb[idx] = f2bf(dec_emb[(size_t)v * 512 + d]);
    }
}

__global__ __launch_bounds__(256) void ctx_mean_k(const u16* __restrict__ ctxB,
                                                  const float* __restrict__ xm,
                                                  u16* __restrict__ cm)
{
    int b = blockIdx.x, tid = threadIdx.x;
    float msum = 0.f;
    for (int t = 0; t < 48; ++t) msum += xm[t * 64 + b];
    float inv = 1.0f / msum;
    for (int e = tid; e < 1024; e += 256) {
        float s = 0.f;
        for (int t = 0; t < 48; ++t)
            s += bf2f(ctxB[(size_t)(t * 64 + b) * 1024 + e]) * xm[t * 64 + b];
        cm[b * 1024 + e] = f2bf(s * inv);
    }
}

__global__ void maxpair(const u16* __restrict__ rB, u16* __restrict__ rmax)
{
    int idx = blockIdx.x * 256 + threadIdx.x;   // 3072*512
    int row = idx >> 9, d = idx & 511;
    float a = bf2f(rB[(size_t)row * 1024 + 2 * d]);
    float b = bf2f(rB[(size_t)row * 1024 + 2 * d + 1]);
    rmax[idx] = f2bf(fmaxf(a, b));
}

__global__ __launch_bounds__(256) void final_sum(const float* __restrict__ lossb,
                                                 float* __restrict__ out)
{
    __shared__ float red[4];
    int tid = threadIdx.x;
    float s = 0.f;
    for (int i = tid; i < 3072; i += 256) s += lossb[i];
    for (int sh = 32; sh; sh >>= 1) s += __shfl_xor(s, sh);
    if ((tid & 63) == 0) red[tid >> 6] = s;
    __syncthreads();
    if (tid == 0) out[0] = red[0] + red[1] + red[2] + red[3];
}

// ---------------------------------------------------------------------------
// Host
// ---------------------------------------------------------------------------
template<int OUTBF, int ACT, int CIN>
static void mg(hipStream_t st, dim3 grid,
               const u16* A, int lda, const u16* B, int ldb,
               const float* bias, const u16* Cin, void* C, int N, int K,
               const u16* A2 = nullptr, const u16* B2 = nullptr,
               const float* bias2 = nullptr, const u16* Cin2 = nullptr, void* C2 = nullptr)
{
    hipLaunchKernelGGL((mgemm<OUTBF, ACT, CIN>), grid, dim3(256), 0, st,
                       A, lda, B, ldb, bias, Cin, C, N, K, A2, B2, bias2, Cin2, C2);
}

extern "C" void kernel_launch(void* const* d_in, const int* in_sizes, int n_in,
                              void* d_out, int out_size, void* d_ws, size_t ws_size,
                              hipStream_t stream)
{
    const int*   x_data    = (const int*)d_in[0];
    const float* x_mask    = (const float*)d_in[1];
    const int*   y_data    = (const int*)d_in[2];
    const float* y_mask    = (const float*)d_in[3];
    const float* src_emb   = (const float*)d_in[4];
    const float* dec_emb   = (const float*)d_in[5];
    const float* enc_Wih_f = (const float*)d_in[6];
    const float* enc_Whh_f = (const float*)d_in[7];
    const float* enc_b_f   = (const float*)d_in[8];
    const float* enc_Wih_r = (const float*)d_in[9];
    const float* enc_Whh_r = (const float*)d_in[10];
    const float* enc_b_r   = (const float*)d_in[11];
    const float* h0_W      = (const float*)d_in[12];
    const float* h0_b      = (const float*)d_in[13];
    const float* c0_W      = (const float*)d_in[14];
    const float* c0_b      = (const float*)d_in[15];
    const float* att1_W    = (const float*)d_in[16];
    const float* att1_b    = (const float*)d_in[17];
    const float* att2_W    = (const float*)d_in[18];
    const float* att2_b    = (const float*)d_in[19];
    const float* cell_Wih  = (const float*)d_in[20];
    const float* cell_Whh  = (const float*)d_in[21];
    const float* cell_b    = (const float*)d_in[22];
    const float* read_W    = (const float*)d_in[23];
    const float* read_b    = (const float*)d_in[24];
    const float* out_W     = (const float*)d_in[25];
    const float* out_b     = (const float*)d_in[26];
    float* out = (float*)d_out;
    (void)in_sizes; (void)n_in; (void)out_size; (void)ws_size;

    char* base = (char*)d_ws;
    size_t off = 0;
    auto ab = [&](size_t bytes) -> void* {
        void* p = base + off;
        off += (bytes + 255) & ~(size_t)255;
        return p;
    };
    u16* WzB     = (u16*)ab(4096UL * 2560 * 2);
    u16* outWB   = (u16*)ab(32000UL * 512 * 2);
    u16* readWB  = (u16*)ab(1024UL * 2560 * 2);
    u16* WihFg   = (u16*)ab(2048UL * 512 * 2);
    u16* WihRg   = (u16*)ab(2048UL * 512 * 2);
    u16* WhhFg   = (u16*)ab(2048UL * 512 * 2);
    u16* WhhRg   = (u16*)ab(2048UL * 512 * 2);
    u16* h0WB    = (u16*)ab(1024UL * 1024 * 2);
    u16* c0WB    = (u16*)ab(1024UL * 1024 * 2);
    u16* W1cB    = (u16*)ab(512UL * 1024 * 2);
    u16* W1yB    = (u16*)ab(512UL * 512 * 2);
    u16* W1hB    = (u16*)ab(512UL * 1024 * 2);
    u16* xembB   = (u16*)ab(3072UL * 512 * 2);
    u16* yembB   = (u16*)ab(3072UL * 512 * 2);
    u16* preAF   = (u16*)ab(3072UL * 2048 * 2);   // dead after encoder
    u16* preAR   = (u16*)ab(3072UL * 2048 * 2);   // dead after encoder
    // G (25.17 MB) aliases preAF+preAR exactly (computed after encoder).
    u16* G       = preAF;
    // Tail buffers alias G (dead after decoder): part | rB | rmaxB
    float2* part = (float2*)preAF;                             // 12,288,000 B
    u16* rB      = (u16*)((char*)preAF + 12288000);            //  6,291,456 B
    u16* rmaxB   = (u16*)((char*)preAF + 12288000 + 6291456);  //  3,145,728 B
    u16* ctxB    = (u16*)ab(3072UL * 1024 * 2);
    u16* attctxB = (u16*)ab(3072UL * 512 * 2);
    u16* preYB   = (u16*)ab(3072UL * 512 * 2);
    u16* cmB     = (u16*)ab(64UL * 1024 * 2);
    u16* hAbuf   = (u16*)ab(49UL * 64 * 512 * 2);   // encoder fwd h rotation
    u16* hBbuf   = (u16*)ab(49UL * 64 * 512 * 2);   // encoder rev h rotation
    u16* htR     = (u16*)ab(49UL * 64 * 1024 * 2);  // decoder ht rotation
    float* ctF   = (float*)ab(64UL * 1024 * 4);
    float* svB   = (float*)ab(48UL * 64 * 512 * 4); // sv rotation
    float* zpartR= (float*)ab(48UL * 64 * 4096 * 4);// zpart rotation (48 MB)
    u16* c3r     = (u16*)ab(3072UL * 2560 * 2);
    float* logy  = (float*)ab(3072UL * 4);
    float* lossb = (float*)ab(3072UL * 4);
    u32* sync    = (u32*)ab(32768);
    u32* decFlags = sync;                 // 256 flags x 16 u32 (64B lines)
    u32* decGo    = sync + 4096;          // 32 replicas x 16 u32
    u32* encSync  = sync + 4608;          // 2 dirs x (64 flags + 16 go) x 16 u32

    // ---- setup ------------------------------------------------------------
    hipMemsetAsync(sync, 0, 32768, stream);
    hipMemsetAsync(hAbuf, 0, 64UL * 512 * 2, stream);   // h_0 fwd = 0
    hipMemsetAsync(hBbuf, 0, 64UL * 512 * 2, stream);   // h_0 rev = 0
    hipLaunchKernelGGL(build_wz_g4, dim3(40960), dim3(256), 0, stream, cell_Wih, cell_Whh, WzB);
    auto conv = [&](const float* src, int sld, int K, u16* dst, size_t total) {
        hipLaunchKernelGGL(convb, dim3((unsigned)((total + 255) / 256)), dim3(256), 0, stream,
                           src, sld, K, dst, (int)total);
    };
    auto convg = [&](const float* src, u16* dst, int H, int K) {
        size_t total = (size_t)4 * H * K;
        hipLaunchKernelGGL(conv_gate4, dim3((unsigned)((total + 255) / 256)), dim3(256), 0, stream,
                           src, dst, H, K, (int)total);
    };
    conv(out_W, 512, 512, outWB, 32000UL * 512);
    conv(read_W, 2560, 2560, readWB, 1024UL * 2560);
    convg(enc_Wih_f, WihFg, 512, 512);
    convg(enc_Wih_r, WihRg, 512, 512);
    convg(enc_Whh_f, WhhFg, 512, 512);
    convg(enc_Whh_r, WhhRg, 512, 512);
    conv(h0_W, 1024, 1024, h0WB, 1024UL * 1024);
    conv(c0_W, 1024, 1024, c0WB, 1024UL * 1024);
    conv(att1_W, 2560, 1024, W1cB, 512UL * 1024);
    conv(att1_W + 1024, 2560, 512, W1yB, 512UL * 512);
    conv(att1_W + 1536, 2560, 1024, W1hB, 512UL * 1024);
    hipLaunchKernelGGL(embed_kernel, dim3(6144, 2), dim3(256), 0, stream,
                       x_data, x_mask, y_data, src_emb, dec_emb, xembB, yembB);

    // preA = x_emb @ Wih'^T (bias added in encoder gates)
    mg<1, 0, 0>(stream, dim3(32, 48, 2), xembB, 512, WihFg, 512, nullptr, nullptr,
                preAF, 2048, 512, xembB, WihRg, nullptr, nullptr, preAR);

    // ---- persistent encoder (128 blocks, hierarchical barriers) -------------
    hipLaunchKernelGGL(enc_persist, dim3(128), dim3(256), 0, stream,
                       WhhFg, WhhRg, preAF, preAR, enc_b_f, enc_b_r, x_mask,
                       hAbuf, hBbuf, ctxB, encSync);

    // ---- G = ctx @ Wz_ctx^T  (overwrites dead preA region) ------------------
    mg<1, 0, 0>(stream, dim3(64, 48, 1), ctxB, 1024, WzB, 2560, nullptr, nullptr,
                G, 4096, 1024);

    // ---- init states + attention precomputes -------------------------------
    hipLaunchKernelGGL(ctx_mean_k, dim3(64), dim3(256), 0, stream, ctxB, x_mask, cmB);
    mg<1, 1, 0>(stream, dim3(16, 1, 1), cmB, 1024, h0WB, 1024, h0_b, nullptr, htR, 1024, 1024);
    mg<0, 1, 0>(stream, dim3(16, 1, 1), cmB, 1024, c0WB, 1024, c0_b, nullptr, ctF, 1024, 1024);
    mg<1, 0, 0>(stream, dim3(8, 48, 1), ctxB, 1024, W1cB, 1024, att1_b, nullptr, attctxB, 512, 1024);
    mg<1, 0, 0>(stream, dim3(8, 48, 1), yembB, 512, W1yB, 512, nullptr, nullptr, preYB, 512, 512);

    // ---- persistent decoder (256 blocks x 512 threads, 2 bars/step) ---------
    hipLaunchKernelGGL(dec_persist, dim3(256), dim3(512), 0, stream,
                       WzB, W1hB, attctxB, ctxB, preYB, yembB, att2_W, att2_b,
                       x_mask, cell_b, htR, ctF, svB, zpartR, G, c3r, decFlags, decGo);

    // ---- batched tail (part/rB/rmaxB alias dead G) --------------------------
    mg<1, 0, 0>(stream, dim3(16, 48, 1), c3r, 2560, readWB, 2560, read_b, nullptr, rB, 1024, 2560);
    hipLaunchKernelGGL(maxpair, dim3(6144), dim3(256), 0, stream, rB, rmaxB);
    hipLaunchKernelGGL(logits_lsm, dim3(48, 500), dim3(256), 0, stream,
                       rmaxB, outWB, out_b, y_data, part, logy);
    hipLaunchKernelGGL(lsm_reduce, dim3(3072), dim3(64), 0, stream, part, logy, y_mask, lossb);
    hipLaunchKernelGGL(final_sum, dim3(1), dim3(256), 0, stream, lossb, out);
}

// Round 15
// 3169.771 us; speedup vs baseline: 1.3731x; 1.3731x over previous
//
#include <hip/hip_runtime.h>
#include <hip/hip_bf16.h>
#include <math.h>

// Tx=48 Ty=48 Bn=64 DW=512 E=512 D=1024 A=512 VS=VT=32000
typedef __attribute__((ext_vector_type(8))) short bf16x8;
typedef __attribute__((ext_vector_type(4))) short bf16x4;
typedef __attribute__((ext_vector_type(4))) float f32x4;
typedef unsigned short u16;
typedef unsigned int u32;

__device__ __forceinline__ float bf2f(u16 u) {
    union { float f; u32 i; } v; v.i = ((u32)u) << 16; return v.f;
}
__device__ __forceinline__ float bflo(u32 v) {
    union { float f; u32 u; } x; x.u = v << 16; return x.f;
}
__device__ __forceinline__ float bfhi(u32 v) {
    union { float f; u32 u; } x; x.u = v & 0xFFFF0000u; return x.f;
}
__device__ __forceinline__ u16 f2bf(float x) {
    union { float f; u32 u; } v; v.f = x;
    u32 r = v.u + 0x7FFF + ((v.u >> 16) & 1);
    return (u16)(r >> 16);
}
__device__ __forceinline__ u32 f2bf2(float a, float b) {
    return (u32)f2bf(a) | ((u32)f2bf(b) << 16);
}
__device__ __forceinline__ float sigf(float x) { return 1.0f / (1.0f + expf(-x)); }

// Write-through stores to the memory-side (L3) coherence point.
__device__ __forceinline__ void st_wt_u16(u16* p, u16 v) {
    asm volatile("global_store_short %0, %1, off sc0 sc1" :: "v"(p), "v"((u32)v) : "memory");
}
__device__ __forceinline__ void st_wt_f32(float* p, float v) {
    asm volatile("global_store_dword %0, %1, off sc0 sc1" :: "v"(p), "v"(v) : "memory");
}
__device__ __forceinline__ void st_wt_u32(u32* p, u32 v) {
    asm volatile("global_store_dword %0, %1, off sc0 sc1" :: "v"(p), "v"(v) : "memory");
}

// Hierarchical barrier: each block wt-stores its own flag (64B-strided line).
// Aggregator block polls ALL flags; broadcasts ph to replicated go-lines;
// every other block polls only its own replica. Waiter spins on the uncached
// load itself (self-throttling ~L3 latency) -- no sleep in the waiter path.
__device__ __forceinline__ void gbarH(u32* flags, u32* go, int myidx, int aggbid,
                                      u32 ph, int nblk, int nrepmask) {
    __syncthreads();
    if ((int)blockIdx.x == aggbid) {
        if (threadIdx.x == 0) st_wt_u32(flags + (size_t)myidx * 16, ph);
        if (threadIdx.x < 64) {
            bool ok = false;
            if (nblk == 256) {
                const u32* p = flags + (size_t)threadIdx.x * 64;
                while (!ok) {
                    u32 a, b, c, d;
                    asm volatile(
                        "global_load_dword %0, %4, off sc0 sc1\n\t"
                        "global_load_dword %1, %5, off sc0 sc1\n\t"
                        "global_load_dword %2, %6, off sc0 sc1\n\t"
                        "global_load_dword %3, %7, off sc0 sc1\n\t"
                        "s_waitcnt vmcnt(0)"
                        : "=&v"(a), "=&v"(b), "=&v"(c), "=&v"(d)
                        : "v"(p), "v"(p + 16), "v"(p + 32), "v"(p + 48)
                        : "memory");
                    ok = __all((a >= ph) && (b >= ph) && (c >= ph) && (d >= ph));
                }
            } else {
                const u32* p = flags + (size_t)threadIdx.x * 16;
                while (!ok) {
                    u32 a;
                    asm volatile("global_load_dword %0, %1, off sc0 sc1\n\ts_waitcnt vmcnt(0)"
                                 : "=&v"(a) : "v"(p) : "memory");
                    ok = __all(a >= ph);
                }
            }
            if ((int)threadIdx.x <= nrepmask)
                st_wt_u32(go + (size_t)threadIdx.x * 16, ph);
        }
        __syncthreads();
    } else {
        if (threadIdx.x == 0) {
            st_wt_u32(flags + (size_t)myidx * 16, ph);
            const u32* gp = go + (size_t)(myidx & nrepmask) * 16;
            u32 v;
            do {
                asm volatile("global_load_dword %0, %1, off sc0 sc1\n\ts_waitcnt vmcnt(0)"
                             : "=&v"(v) : "v"(gp) : "memory");
            } while (v < ph);
        }
        __syncthreads();
    }
}

// ---------------------------------------------------------------------------
// MFMA GEMM (batched ops): C = act(A@B^T + bias + Cin), 64x64 tile.
// ---------------------------------------------------------------------------
template<int OUTBF, int ACT, int CIN>
__global__ __launch_bounds__(256) void mgemm(
    const u16* __restrict__ A, int lda,
    const u16* __restrict__ B, int ldb,
    const float* __restrict__ bias,
    const u16* __restrict__ Cin,
    void* __restrict__ Cout,
    int N, int K,
    const u16* A2, const u16* B2, const float* bias2, const u16* Cin2, void* Cout2)
{
    if (blockIdx.z == 1) { A = A2; B = B2; bias = bias2; Cin = Cin2; Cout = Cout2; }
    const int lane = threadIdx.x & 63;
    const int wave = threadIdx.x >> 6;
    const int wm = wave >> 1, wn = wave & 1;
    const int lr = lane & 15, lg = lane >> 4;
    const size_t bm = (size_t)blockIdx.y * 64, bn = (size_t)blockIdx.x * 64;
    const u16* Ap = A + (bm + wm * 32 + lr) * (size_t)lda + lg * 8;
    const u16* Bp = B + (bn + wn * 32 + lr) * (size_t)ldb + lg * 8;
    f32x4 acc[2][2] = {};
    for (int k0 = 0; k0 < K; k0 += 32) {
        bf16x8 a0 = *(const bf16x8*)(Ap + k0);
        bf16x8 a1 = *(const bf16x8*)(Ap + k0 + 16 * (size_t)lda);
        bf16x8 b0 = *(const bf16x8*)(Bp + k0);
        bf16x8 b1 = *(const bf16x8*)(Bp + k0 + 16 * (size_t)ldb);
        acc[0][0] = __builtin_amdgcn_mfma_f32_16x16x32_bf16(a0, b0, acc[0][0], 0, 0, 0);
        acc[0][1] = __builtin_amdgcn_mfma_f32_16x16x32_bf16(a0, b1, acc[0][1], 0, 0, 0);
        acc[1][0] = __builtin_amdgcn_mfma_f32_16x16x32_bf16(a1, b0, acc[1][0], 0, 0, 0);
        acc[1][1] = __builtin_amdgcn_mfma_f32_16x16x32_bf16(a1, b1, acc[1][1], 0, 0, 0);
    }
    #pragma unroll
    for (int fi = 0; fi < 2; ++fi)
    #pragma unroll
    for (int fj = 0; fj < 2; ++fj) {
        size_t col = bn + wn * 32 + fj * 16 + lr;
        float bv = bias ? bias[col] : 0.0f;
        #pragma unroll
        for (int r = 0; r < 4; ++r) {
            size_t row = bm + wm * 32 + fi * 16 + lg * 4 + r;
            float v = acc[fi][fj][r] + bv;
            if constexpr (CIN) v += bf2f(Cin[row * (size_t)N + col]);
            if constexpr (ACT) v = tanhf(v);
            if constexpr (OUTBF) ((u16*)Cout)[row * (size_t)N + col] = f2bf(v);
            else                 ((float*)Cout)[row * (size_t)N + col] = v;
        }
    }
}

// ---------------------------------------------------------------------------
// Persistent encoder: 128 blocks (dir = bid>>6), Whh slice in LDS.
// h rotates per step (fresh address): wt-stores + normal reads. 1 bar/step.
// ---------------------------------------------------------------------------
__global__ __launch_bounds__(256, 1) void enc_persist(
    const u16* __restrict__ WhhFg, const u16* __restrict__ WhhRg,
    const u16* __restrict__ preAF, const u16* __restrict__ preAR,
    const float* __restrict__ bF, const float* __restrict__ bR,
    const float* __restrict__ xm,
    u16* hAbuf, u16* hBbuf,
    u16* __restrict__ ctxB, u32* encSync)
{
    const int tid = threadIdx.x, bid = blockIdx.x;
    const int lane = tid & 63, wave = tid >> 6;
    const int lr = lane & 15, lg = lane >> 4;
    const int dir = bid >> 6;
    const int nb = bid & 63;
    const u16* Whh = dir ? WhhRg : WhhFg;
    const u16* preA = dir ? preAR : preAF;
    const float* bias = dir ? bR : bF;
    u16* hbase = dir ? hBbuf : hAbuf;
    u32* flags = encSync + (size_t)dir * 1280;
    u32* go = flags + 1024;
    const int aggbid = dir * 64;
    __shared__ u16 whh[32 * 520];
    __shared__ float zs[64 * 33];
    for (int i = tid; i < 32 * 64; i += 256) {
        int r = i >> 6, c = (i & 63) * 8;
        *(bf16x8*)&whh[r * 520 + c] = *(const bf16x8*)&Whh[(size_t)(nb * 32 + r) * 512 + c];
    }
    __syncthreads();
    const int gb = tid & 63, dl0 = tid >> 6;
    float creg[2] = {0.f, 0.f};
    u32 ph = 0;
    for (int s = 0; s < 48; ++s) {
        const int t = dir ? (47 - s) : s;
        if (s > 0) {
            const u16* hc = hbase + (size_t)s * 32768;
            const u16* Ap = hc + (wave * 16 + lr) * 512 + lg * 8;
            f32x4 acc0 = {}, acc1 = {};
            #pragma unroll 4
            for (int k0 = 0; k0 < 512; k0 += 32) {
                bf16x8 a  = *(const bf16x8*)(Ap + k0);
                bf16x8 b0 = *(const bf16x8*)&whh[lr * 520 + k0 + lg * 8];
                bf16x8 b1 = *(const bf16x8*)&whh[(16 + lr) * 520 + k0 + lg * 8];
                acc0 = __builtin_amdgcn_mfma_f32_16x16x32_bf16(a, b0, acc0, 0, 0, 0);
                acc1 = __builtin_amdgcn_mfma_f32_16x16x32_bf16(a, b1, acc1, 0, 0, 0);
            }
            #pragma unroll
            for (int r = 0; r < 4; ++r) {
                int row = wave * 16 + lg * 4 + r;
                zs[row * 33 + lr] = acc0[r];
                zs[row * 33 + 16 + lr] = acc1[r];
            }
            __syncthreads();
        }
        u16* hnx = hbase + (size_t)(s + 1) * 32768;
        #pragma unroll
        for (int q = 0; q < 2; ++q) {
            int dl = dl0 + q * 4;
            int dg = nb * 8 + dl;
            bf16x4 pa = *(const bf16x4*)&preA[((size_t)t * 64 + gb) * 2048 + nb * 32 + 4 * dl];
            float iv = bf2f((u16)pa[0]) + bias[dg];
            float fv = bf2f((u16)pa[1]) + bias[512 + dg];
            float gv = bf2f((u16)pa[2]) + bias[1024 + dg];
            float ov = bf2f((u16)pa[3]) + bias[1536 + dg];
            if (s > 0) {
                iv += zs[gb * 33 + 4 * dl + 0];
                fv += zs[gb * 33 + 4 * dl + 1];
                gv += zs[gb * 33 + 4 * dl + 2];
                ov += zs[gb * 33 + 4 * dl + 3];
            }
            float cn = sigf(fv) * creg[q] + sigf(iv) * tanhf(gv);
            float hn = sigf(ov) * tanhf(cn);
            creg[q] = cn;
            st_wt_u16(&hnx[gb * 512 + dg], f2bf(hn));
            ctxB[((size_t)t * 64 + gb) * 1024 + dir * 512 + dg] = f2bf(hn * xm[t * 64 + gb]);
        }
        if (s < 47) gbarH(flags, go, nb, aggbid, ++ph, 64, 15);
    }
}

// ---------------------------------------------------------------------------
// Persistent decoder: 256 blocks x 512 threads, hierarchical barriers.
// G fragment (step-invariant addresses) hoisted into 48 persistent VGPRs:
// the Z phase is pure register FMA + one 12KB alpha stage.
// Phases/step: att -> bar -> Z(reg) -> bar -> svz -> bar.
// ---------------------------------------------------------------------------
__global__ __launch_bounds__(512, 1) void dec_persist(
    const u16* __restrict__ WzB, const u16* __restrict__ W1hB,
    const u16* __restrict__ attctxB, const u16* __restrict__ ctxB,
    const u16* __restrict__ preYB, const u16* __restrict__ yembB,
    const float* __restrict__ att2W, const float* __restrict__ att2b,
    const float* __restrict__ xmask, const float* __restrict__ cellb,
    u16* htR, const float* __restrict__ ctF,
    float* svB, float* alphaB, const u16* __restrict__ G,
    u16* c3r, u32* decFlags, u32* decGo)
{
    const int tid = threadIdx.x, bid = blockIdx.x;
    const int lane = tid & 63, wave = tid >> 6;
    const int lr = lane & 15, lg = lane >> 4;
    // XCD-friendly column-block swizzle (bijective; perf heuristic only)
    const int cb = ((bid & 7) << 5) | (bid >> 3);
    __shared__ u16 wzl[16 * 1544];   // Wz [ht|yemb] cols for this block's 16 rows
    __shared__ u16 w1h[2 * 1024];
    __shared__ u16 big[48 * 512];    // attctx for batch row ab (att blocks)
    __shared__ float alds[48 * 64];  // alpha staging
    __shared__ float zp[64][17];     // zpart from svz
    __shared__ float zred[8 * 64 * 17]; // Z partials; sv transpose scratch
    __shared__ float a2s[64];

    // ---- one-time staging ----
    for (int i = tid; i < 16 * 192; i += 512) {
        int r = i / 192, c = (i % 192) * 8;
        *(bf16x8*)&wzl[r * 1544 + c] =
            *(const bf16x8*)&WzB[(size_t)(cb * 16 + r) * 2560 + 1024 + c];
    }
    for (int i = tid; i < 256; i += 512) {
        int r = i >> 7, c = (i & 127) * 8;
        *(bf16x8*)&w1h[r * 1024 + c] = *(const bf16x8*)&W1hB[(size_t)(bid * 2 + r) * 1024 + c];
    }
    const int isatt = (bid < 128);
    const int ab = bid >> 1;
    const int eh = bid & 1;
    u32 ctxr[48];
    float a2wreg[8];
    float xmr = 0.f;
    if (isatt) {
        for (int i = tid; i < 48 * 64; i += 512) {
            int tp = i >> 6, c = (i & 63) * 8;
            *(bf16x8*)&big[tp * 512 + c] =
                *(const bf16x8*)&attctxB[((size_t)tp * 64 + ab) * 512 + c];
        }
        if (tid < 256) {
            #pragma unroll
            for (int tp = 0; tp < 48; ++tp)
                ctxr[tp] = *(const u32*)&ctxB[((size_t)tp * 64 + ab) * 1024 + eh * 512 + 2 * tid];
        }
        #pragma unroll
        for (int k = 0; k < 8; ++k) a2wreg[k] = att2W[k * 64 + lane];
        if (tid < 64) xmr = xmask[tid * 64 + ab];
    }
    // ---- hoist G fragment into registers (addresses step-invariant) ----
    const int grp = tid >> 6;       // 0..7, covers tp = grp*6 + 0..5
    const int zgb = tid & 63;
    uint4 gfrag[12];
    #pragma unroll
    for (int u = 0; u < 6; ++u) {
        const u16* gr = G + ((size_t)(grp * 6 + u) * 64 + zgb) * 4096 + cb * 16;
        gfrag[2 * u]     = *(const uint4*)(gr);
        gfrag[2 * u + 1] = *(const uint4*)(gr + 8);
    }
    __syncthreads();   // LDS staging complete before any reads

    const float att2b0 = att2b[0];
    const int gb = tid & 63, gdd = (tid >> 6) & 3;
    const int gd = cb * 4 + gdd;                 // this thread's d-column
    float cb_reg[4];
    float ct_reg = 0.f;
    if (tid < 256) {
        #pragma unroll
        for (int g = 0; g < 4; ++g) cb_reg[g] = cellb[g * 1024 + gd];
        ct_reg = ctF[gb * 1024 + gd];
    }

    // sv GEMV (waves 0-3, MLP-batched partials + LDS transpose reduce)
    // || zpart GEMM [ht|yemb]@Wz_yh (waves 4-7) for step tt
    auto svz_phase = [&](int tt) {
        const u16* htT = htR + (size_t)tt * 65536;
        if (wave < 4) {
            const int jl = wave & 1;
            const int bh = wave >> 1;
            const int j = bid * 2 + jl;
            float* svT = svB + (size_t)tt * 32768;
            bf16x8 wv0 = *(const bf16x8*)&w1h[jl * 1024 + lane * 8];
            bf16x8 wv1 = *(const bf16x8*)&w1h[jl * 1024 + 512 + lane * 8];
            float s[32];
            #pragma unroll 8
            for (int bi = 0; bi < 32; ++bi) {
                const u16* hp = htT + (bh * 32 + bi) * 1024 + lane * 8;
                bf16x8 h0 = *(const bf16x8*)(hp);
                bf16x8 h1 = *(const bf16x8*)(hp + 512);
                float a = 0.f;
                #pragma unroll
                for (int u = 0; u < 8; ++u)
                    a += bf2f((u16)h0[u]) * bf2f((u16)wv0[u])
                       + bf2f((u16)h1[u]) * bf2f((u16)wv1[u]);
                s[bi] = a;
            }
            // per-wave transpose scratch: 32 rows x 65 floats (conflict-free)
            float* zone = zred + wave * 2080;
            #pragma unroll 8
            for (int bi = 0; bi < 32; ++bi) zone[bi * 65 + lane] = s[bi];
            if (lane < 32) {
                const float* zr = zone + lane * 65;
                float tsum = 0.f;
                #pragma unroll
                for (int q = 0; q < 64; ++q) tsum += zr[q];
                int b = bh * 32 + lane;
                st_wt_f32(&svT[b * 512 + j],
                          tsum + bf2f(preYB[((size_t)tt * 64 + b) * 512 + j]));
            }
        } else {
            const int q = wave - 4;
            const u16* Ah = htT + (q * 16 + lr) * 1024 + lg * 8;
            const u16* Ay = yembB + ((size_t)tt * 64 + q * 16 + lr) * 512 + lg * 8;
            const u16* Bp = &wzl[lr * 1544 + lg * 8];
            f32x4 acc = {};
            #pragma unroll 4
            for (int k0 = 0; k0 < 1024; k0 += 32) {
                bf16x8 a = *(const bf16x8*)(Ah + k0);
                bf16x8 b = *(const bf16x8*)(Bp + k0);
                acc = __builtin_amdgcn_mfma_f32_16x16x32_bf16(a, b, acc, 0, 0, 0);
            }
            #pragma unroll 4
            for (int k0 = 0; k0 < 512; k0 += 32) {
                bf16x8 a = *(const bf16x8*)(Ay + k0);
                bf16x8 b = *(const bf16x8*)(Bp + 1024 + k0);
                acc = __builtin_amdgcn_mfma_f32_16x16x32_bf16(a, b, acc, 0, 0, 0);
            }
            #pragma unroll
            for (int r = 0; r < 4; ++r)
                zp[q * 16 + lg * 4 + r][lr] = acc[r];
        }
    };

    u32 ph = 0;
    svz_phase(0);
    gbarH(decFlags, decGo, bid, 255, ++ph, 256, 31);

    for (int t = 0; t < 48; ++t) {
        // ---- A: attention (blocks 0..127): scores -> alpha; ctx_t -> c3r ----
        if (isatt) {
            const float* svT = svB + (size_t)t * 32768;
            float svr[8];
            #pragma unroll
            for (int k = 0; k < 8; ++k) svr[k] = svT[ab * 512 + k * 64 + lane];
            for (int tp = wave; tp < 48; tp += 8) {
                float s = 0.f;
                #pragma unroll
                for (int k = 0; k < 8; ++k)
                    s += a2wreg[k] * tanhf(bf2f(big[tp * 512 + k * 64 + lane]) + svr[k]);
                #pragma unroll
                for (int m = 32; m; m >>= 1) s += __shfl_xor(s, m);
                if (lane == 0) a2s[tp] = s + att2b0;
            }
            __syncthreads();
            if (tid < 64) {
                float v = (tid < 48) ? a2s[tid] : -1e30f;
                float m = v;
                #pragma unroll
                for (int sh = 32; sh; sh >>= 1) m = fmaxf(m, __shfl_xor(m, sh));
                float e = (tid < 48) ? expf(v - m) * xmr : 0.f;
                float ssum = e;
                #pragma unroll
                for (int sh = 32; sh; sh >>= 1) ssum += __shfl_xor(ssum, sh);
                if (tid < 48) a2s[tid] = e / (ssum + 1e-15f);
            }
            __syncthreads();
            u16* c3rt = c3r + (size_t)t * 64 * 2560;
            if (tid < 256) {
                float c0 = 0.f, c1 = 0.f;
                #pragma unroll
                for (int tp = 0; tp < 48; ++tp) {
                    float al = a2s[tp]; u32 cv = ctxr[tp];
                    c0 += al * bflo(cv); c1 += al * bfhi(cv);
                }
                *(u32*)&c3rt[ab * 2560 + eh * 512 + 2 * tid] = f2bf2(c0, c1);
            } else if (tid < 384) {
                int i = tid - 256;
                *(u32*)&c3rt[ab * 2560 + 2048 + eh * 256 + 2 * i] =
                    *(const u32*)&yembB[((size_t)t * 64 + ab) * 512 + eh * 256 + 2 * i];
            }
            if (eh == 0 && tid < 48)
                st_wt_f32(&alphaB[(size_t)t * 3072 + tid * 64 + ab], a2s[tid]);
        }
        gbarH(decFlags, decGo, bid, 255, ++ph, 256, 31);
        // ---- Z: z = alpha.Gfrag(reg) + zpart + bias -> gates -> new ht ----
        {
            const float* alT = alphaB + (size_t)t * 3072;
            for (int i = tid; i < 3072; i += 512) alds[i] = alT[i];
            __syncthreads();
            {
                float pz[16] = {};
                #pragma unroll
                for (int u = 0; u < 6; ++u) {
                    float al = alds[(grp * 6 + u) * 64 + zgb];
                    uint4 g0 = gfrag[2 * u];
                    uint4 g1 = gfrag[2 * u + 1];
                    pz[0]  += al * bflo(g0.x); pz[1]  += al * bfhi(g0.x);
                    pz[2]  += al * bflo(g0.y); pz[3]  += al * bfhi(g0.y);
                    pz[4]  += al * bflo(g0.z); pz[5]  += al * bfhi(g0.z);
                    pz[6]  += al * bflo(g0.w); pz[7]  += al * bfhi(g0.w);
                    pz[8]  += al * bflo(g1.x); pz[9]  += al * bfhi(g1.x);
                    pz[10] += al * bflo(g1.y); pz[11] += al * bfhi(g1.y);
                    pz[12] += al * bflo(g1.z); pz[13] += al * bfhi(g1.z);
                    pz[14] += al * bflo(g1.w); pz[15] += al * bfhi(g1.w);
                }
                float* zr = &zred[(grp * 64 + zgb) * 17];
                #pragma unroll
                for (int c = 0; c < 16; ++c) zr[c] = pz[c];
            }
            __syncthreads();
            if (tid < 256) {
                float zv[4];
                #pragma unroll
                for (int g = 0; g < 4; ++g) {
                    int c = 4 * gdd + g;
                    float s = cb_reg[g] + zp[gb][c];
                    #pragma unroll
                    for (int grp2 = 0; grp2 < 8; ++grp2)
                        s += zred[(grp2 * 64 + gb) * 17 + c];
                    zv[g] = s;
                }
                float cn = sigf(zv[1]) * ct_reg + sigf(zv[0]) * tanhf(zv[2]);
                float hn = sigf(zv[3]) * tanhf(cn);
                ct_reg = cn;
                u16 hb = f2bf(hn);
                st_wt_u16(&htR[(size_t)(t + 1) * 65536 + gb * 1024 + gd], hb);
                c3r[(size_t)t * 64 * 2560 + gb * 2560 + 1024 + gd] = hb;
            }
        }
        if (t < 47) {
            gbarH(decFlags, decGo, bid, 255, ++ph, 256, 31);
            svz_phase(t + 1);
            gbarH(decFlags, decGo, bid, 255, ++ph, 256, 31);
        }
    }
}

// ---------------------------------------------------------------------------
// Fused logits GEMM + partial log-softmax. Grid (48, 500): consecutive blocks
// share the same out_W panel (B read once; A stays L2-resident).
// ---------------------------------------------------------------------------
__global__ __launch_bounds__(256) void logits_lsm(
    const u16* __restrict__ A, const u16* __restrict__ B,
    const float* __restrict__ outb, const int* __restrict__ ydata,
    float2* __restrict__ part, float* __restrict__ logy)
{
    const int lane = threadIdx.x & 63;
    const int wave = threadIdx.x >> 6;
    const int wm = wave >> 1, wn = wave & 1;
    const int lr = lane & 15, lg = lane >> 4;
    const size_t bm = (size_t)blockIdx.x * 64, bn = (size_t)blockIdx.y * 64;
    const u16* Ap = A + (bm + wm * 32 + lr) * 512 + lg * 8;
    const u16* Bp = B + (bn + wn * 32 + lr) * 512 + lg * 8;
    f32x4 acc[2][2] = {};
    for (int k0 = 0; k0 < 512; k0 += 32) {
        bf16x8 a0 = *(const bf16x8*)(Ap + k0);
        bf16x8 a1 = *(const bf16x8*)(Ap + k0 + 16 * 512);
        bf16x8 b0 = *(const bf16x8*)(Bp + k0);
        bf16x8 b1 = *(const bf16x8*)(Bp + k0 + 16 * 512);
        acc[0][0] = __builtin_amdgcn_mfma_f32_16x16x32_bf16(a0, b0, acc[0][0], 0, 0, 0);
        acc[0][1] = __builtin_amdgcn_mfma_f32_16x16x32_bf16(a0, b1, acc[0][1], 0, 0, 0);
        acc[1][0] = __builtin_amdgcn_mfma_f32_16x16x32_bf16(a1, b0, acc[1][0], 0, 0, 0);
        acc[1][1] = __builtin_amdgcn_mfma_f32_16x16x32_bf16(a1, b1, acc[1][1], 0, 0, 0);
    }
    __shared__ float sm[64][2];
    __shared__ float ss[64][2];
    const float b0 = outb[bn + wn * 32 + lr];
    const float b1 = outb[bn + wn * 32 + 16 + lr];
    #pragma unroll
    for (int fi = 0; fi < 2; ++fi) {
        #pragma unroll
        for (int r = 0; r < 4; ++r) {
            int rloc = wm * 32 + fi * 16 + lg * 4 + r;
            size_t row = bm + rloc;
            float v0 = acc[fi][0][r] + b0;
            float v1 = acc[fi][1][r] + b1;
            int yt = ydata[row];
            if (yt == (int)(bn + wn * 32 + lr))      logy[row] = v0;
            if (yt == (int)(bn + wn * 32 + 16 + lr)) logy[row] = v1;
            float m = fmaxf(v0, v1);
            #pragma unroll
            for (int sh = 1; sh < 16; sh <<= 1) m = fmaxf(m, __shfl_xor(m, sh));
            float s = expf(v0 - m) + expf(v1 - m);
            #pragma unroll
            for (int sh = 1; sh < 16; sh <<= 1) s += __shfl_xor(s, sh);
            if (lr == 0) { sm[rloc][wn] = m; ss[rloc][wn] = s; }
        }
    }
    __syncthreads();
    if (threadIdx.x < 64) {
        float m0 = sm[threadIdx.x][0], m1 = sm[threadIdx.x][1];
        float m = fmaxf(m0, m1);
        float s = ss[threadIdx.x][0] * expf(m0 - m) + ss[threadIdx.x][1] * expf(m1 - m);
        part[(bm + threadIdx.x) * 500 + blockIdx.y] = make_float2(m, s);
    }
}

__global__ __launch_bounds__(64) void lsm_reduce(
    const float2* __restrict__ part, const float* __restrict__ logy,
    const float* __restrict__ ymask, float* __restrict__ lossb)
{
    int r = blockIdx.x, lane = threadIdx.x;
    float m = -1e30f;
    for (int i = lane; i < 500; i += 64) m = fmaxf(m, part[(size_t)r * 500 + i].x);
    #pragma unroll
    for (int sh = 32; sh; sh >>= 1) m = fmaxf(m, __shfl_xor(m, sh));
    float s = 0.f;
    for (int i = lane; i < 500; i += 64) {
        float2 p = part[(size_t)r * 500 + i];
        s += p.y * expf(p.x - m);
    }
    #pragma unroll
    for (int sh = 32; sh; sh >>= 1) s += __shfl_xor(s, sh);
    if (lane == 0) {
        float lp = logy[r] - m - logf(s);
        lossb[r] = -lp * ymask[r] * (1.0f / 64.0f);
    }
}

// ---------------------------------------------------------------------------
// Small kernels
// ---------------------------------------------------------------------------
__global__ void convb(const float* __restrict__ src, int sld, int K,
                      u16* __restrict__ dst, int total)
{
    int idx = blockIdx.x * 256 + threadIdx.x;
    if (idx >= total) return;
    int n = idx / K, k = idx - n * K;
    dst[idx] = f2bf(src[(size_t)n * sld + k]);
}

__global__ void conv_gate4(const float* __restrict__ src, u16* __restrict__ dst,
                           int H, int K, int total)
{
    int idx = blockIdx.x * 256 + threadIdx.x;
    if (idx >= total) return;
    int n = idx / K, k = idx - n * K;
    int d = n >> 2, g = n & 3;
    dst[idx] = f2bf(src[(size_t)(g * H + d) * K + k]);
}

__global__ void build_wz_g4(const float* __restrict__ Wih, const float* __restrict__ Whh,
                            u16* __restrict__ Wz)
{
    int idx = blockIdx.x * 256 + threadIdx.x;  // 4096*2560
    int j = idx % 2560, np = idx / 2560;
    int n = (np & 3) * 1024 + (np >> 2);
    float v;
    if (j < 1024)      v = Wih[(size_t)n * 1536 + 512 + j];
    else if (j < 2048) v = Whh[(size_t)n * 1024 + (j - 1024)];
    else               v = Wih[(size_t)n * 1536 + (j - 2048)];
    Wz[idx] = f2bf(v);
}

__global__ void embed_kernel(const int* __restrict__ xd, const float* __restrict__ xm,
                             const int* __restrict__ yd,
                             const float* __restrict__ src_emb, const float* __restrict__ dec_emb,
                             u16* __restrict__ x_emb, u16* __restrict__ y_emb)
{
    int idx = blockIdx.x * 256 + threadIdx.x;   // 48*64*512
    int d = idx & 511;
    int tb = idx >> 9;
    if (blockIdx.y == 0) {
        int v = xd[tb];
        x_emb[idx] = f2bf(src_emb[(size_t)v * 512 + d] * xm[tb]);
    } else {
        int t = tb >> 6, b = tb & 63;
        int v = (t == 0) ? 0 : yd[(t - 1) * 64 + b];
        y_emb[idx] = f2bf(dec_emb[(size_t)v * 512 + d]);
    }
}

__global__ __launch_bounds__(256) void ctx_mean_k(const u16* __restrict__ ctxB,
                                                  const float* __restrict__ xm,
                                                  u16* __restrict__ cm)
{
    int b = blockIdx.x, tid = threadIdx.x;
    float msum = 0.f;
    for (int t = 0; t < 48; ++t) msum += xm[t * 64 + b];
    float inv = 1.0f / msum;
    for (int e = tid; e < 1024; e += 256) {
        float s = 0.f;
        for (int t = 0; t < 48; ++t)
            s += bf2f(ctxB[(size_t)(t * 64 + b) * 1024 + e]) * xm[t * 64 + b];
        cm[b * 1024 + e] = f2bf(s * inv);
    }
}

__global__ void maxpair(const u16* __restrict__ rB, u16* __restrict__ rmax)
{
    int idx = blockIdx.x * 256 + threadIdx.x;   // 3072*512
    int row = idx >> 9, d = idx & 511;
    float a = bf2f(rB[(size_t)row * 1024 + 2 * d]);
    float b = bf2f(rB[(size_t)row * 1024 + 2 * d + 1]);
    rmax[idx] = f2bf(fmaxf(a, b));
}

__global__ __launch_bounds__(256) void final_sum(const float* __restrict__ lossb,
                                                 float* __restrict__ out)
{
    __shared__ float red[4];
    int tid = threadIdx.x;
    float s = 0.f;
    for (int i = tid; i < 3072; i += 256) s += lossb[i];
    for (int sh = 32; sh; sh >>= 1) s += __shfl_xor(s, sh);
    if ((tid & 63) == 0) red[tid >> 6] = s;
    __syncthreads();
    if (tid == 0) out[0] = red[0] + red[1] + red[2] + red[3];
}

// ---------------------------------------------------------------------------
// Host
// ---------------------------------------------------------------------------
template<int OUTBF, int ACT, int CIN>
static void mg(hipStream_t st, dim3 grid,
               const u16* A, int lda, const u16* B, int ldb,
               const float* bias, const u16* Cin, void* C, int N, int K,
               const u16* A2 = nullptr, const u16* B2 = nullptr,
               const float* bias2 = nullptr, const u16* Cin2 = nullptr, void* C2 = nullptr)
{
    hipLaunchKernelGGL((mgemm<OUTBF, ACT, CIN>), grid, dim3(256), 0, st,
                       A, lda, B, ldb, bias, Cin, C, N, K, A2, B2, bias2, Cin2, C2);
}

extern "C" void kernel_launch(void* const* d_in, const int* in_sizes, int n_in,
                              void* d_out, int out_size, void* d_ws, size_t ws_size,
                              hipStream_t stream)
{
    const int*   x_data    = (const int*)d_in[0];
    const float* x_mask    = (const float*)d_in[1];
    const int*   y_data    = (const int*)d_in[2];
    const float* y_mask    = (const float*)d_in[3];
    const float* src_emb   = (const float*)d_in[4];
    const float* dec_emb   = (const float*)d_in[5];
    const float* enc_Wih_f = (const float*)d_in[6];
    const float* enc_Whh_f = (const float*)d_in[7];
    const float* enc_b_f   = (const float*)d_in[8];
    const float* enc_Wih_r = (const float*)d_in[9];
    const float* enc_Whh_r = (const float*)d_in[10];
    const float* enc_b_r   = (const float*)d_in[11];
    const float* h0_W      = (const float*)d_in[12];
    const float* h0_b      = (const float*)d_in[13];
    const float* c0_W      = (const float*)d_in[14];
    const float* c0_b      = (const float*)d_in[15];
    const float* att1_W    = (const float*)d_in[16];
    const float* att1_b    = (const float*)d_in[17];
    const float* att2_W    = (const float*)d_in[18];
    const float* att2_b    = (const float*)d_in[19];
    const float* cell_Wih  = (const float*)d_in[20];
    const float* cell_Whh  = (const float*)d_in[21];
    const float* cell_b    = (const float*)d_in[22];
    const float* read_W    = (const float*)d_in[23];
    const float* read_b    = (const float*)d_in[24];
    const float* out_W     = (const float*)d_in[25];
    const float* out_b     = (const float*)d_in[26];
    float* out = (float*)d_out;
    (void)in_sizes; (void)n_in; (void)out_size; (void)ws_size;

    char* base = (char*)d_ws;
    size_t off = 0;
    auto ab = [&](size_t bytes) -> void* {
        void* p = base + off;
        off += (bytes + 255) & ~(size_t)255;
        return p;
    };
    u16* WzB     = (u16*)ab(4096UL * 2560 * 2);
    u16* outWB   = (u16*)ab(32000UL * 512 * 2);
    u16* readWB  = (u16*)ab(1024UL * 2560 * 2);
    u16* WihFg   = (u16*)ab(2048UL * 512 * 2);
    u16* WihRg   = (u16*)ab(2048UL * 512 * 2);
    u16* WhhFg   = (u16*)ab(2048UL * 512 * 2);
    u16* WhhRg   = (u16*)ab(2048UL * 512 * 2);
    u16* h0WB    = (u16*)ab(1024UL * 1024 * 2);
    u16* c0WB    = (u16*)ab(1024UL * 1024 * 2);
    u16* W1cB    = (u16*)ab(512UL * 1024 * 2);
    u16* W1yB    = (u16*)ab(512UL * 512 * 2);
    u16* W1hB    = (u16*)ab(512UL * 1024 * 2);
    u16* xembB   = (u16*)ab(3072UL * 512 * 2);
    u16* yembB   = (u16*)ab(3072UL * 512 * 2);
    u16* preAF   = (u16*)ab(3072UL * 2048 * 2);   // dead after encoder
    u16* preAR   = (u16*)ab(3072UL * 2048 * 2);   // dead after encoder
    // G (25.17 MB) aliases preAF+preAR exactly (computed after encoder).
    u16* G       = preAF;
    // Tail buffers alias G (dead after decoder): part | rB | rmaxB
    float2* part = (float2*)preAF;                             // 12,288,000 B
    u16* rB      = (u16*)((char*)preAF + 12288000);            //  6,291,456 B
    u16* rmaxB   = (u16*)((char*)preAF + 12288000 + 6291456);  //  3,145,728 B
    u16* ctxB    = (u16*)ab(3072UL * 1024 * 2);
    u16* attctxB = (u16*)ab(3072UL * 512 * 2);
    u16* preYB   = (u16*)ab(3072UL * 512 * 2);
    u16* cmB     = (u16*)ab(64UL * 1024 * 2);
    u16* hAbuf   = (u16*)ab(49UL * 64 * 512 * 2);   // encoder fwd h rotation
    u16* hBbuf   = (u16*)ab(49UL * 64 * 512 * 2);   // encoder rev h rotation
    u16* htR     = (u16*)ab(49UL * 64 * 1024 * 2);  // decoder ht rotation
    float* ctF   = (float*)ab(64UL * 1024 * 4);
    float* svB   = (float*)ab(48UL * 64 * 512 * 4); // sv rotation
    float* alphaB= (float*)ab(48UL * 3072 * 4);     // alpha rotation
    u16* c3r     = (u16*)ab(3072UL * 2560 * 2);
    float* logy  = (float*)ab(3072UL * 4);
    float* lossb = (float*)ab(3072UL * 4);
    u32* sync    = (u32*)ab(32768);
    u32* decFlags = sync;                 // 256 flags x 16 u32 (64B lines)
    u32* decGo    = sync + 4096;          // 32 replicas x 16 u32
    u32* encSync  = sync + 4608;          // 2 dirs x (64 flags + 16 go) x 16 u32

    // ---- setup ------------------------------------------------------------
    hipMemsetAsync(sync, 0, 32768, stream);
    hipMemsetAsync(hAbuf, 0, 64UL * 512 * 2, stream);   // h_0 fwd = 0
    hipMemsetAsync(hBbuf, 0, 64UL * 512 * 2, stream);   // h_0 rev = 0
    hipLaunchKernelGGL(build_wz_g4, dim3(40960), dim3(256), 0, stream, cell_Wih, cell_Whh, WzB);
    auto conv = [&](const float* src, int sld, int K, u16* dst, size_t total) {
        hipLaunchKernelGGL(convb, dim3((unsigned)((total + 255) / 256)), dim3(256), 0, stream,
                           src, sld, K, dst, (int)total);
    };
    auto convg = [&](const float* src, u16* dst, int H, int K) {
        size_t total = (size_t)4 * H * K;
        hipLaunchKernelGGL(conv_gate4, dim3((unsigned)((total + 255) / 256)), dim3(256), 0, stream,
                           src, dst, H, K, (int)total);
    };
    conv(out_W, 512, 512, outWB, 32000UL * 512);
    conv(read_W, 2560, 2560, readWB, 1024UL * 2560);
    convg(enc_Wih_f, WihFg, 512, 512);
    convg(enc_Wih_r, WihRg, 512, 512);
    convg(enc_Whh_f, WhhFg, 512, 512);
    convg(enc_Whh_r, WhhRg, 512, 512);
    conv(h0_W, 1024, 1024, h0WB, 1024UL * 1024);
    conv(c0_W, 1024, 1024, c0WB, 1024UL * 1024);
    conv(att1_W, 2560, 1024, W1cB, 512UL * 1024);
    conv(att1_W + 1024, 2560, 512, W1yB, 512UL * 512);
    conv(att1_W + 1536, 2560, 1024, W1hB, 512UL * 1024);
    hipLaunchKernelGGL(embed_kernel, dim3(6144, 2), dim3(256), 0, stream,
                       x_data, x_mask, y_data, src_emb, dec_emb, xembB, yembB);

    // preA = x_emb @ Wih'^T (bias added in encoder gates)
    mg<1, 0, 0>(stream, dim3(32, 48, 2), xembB, 512, WihFg, 512, nullptr, nullptr,
                preAF, 2048, 512, xembB, WihRg, nullptr, nullptr, preAR);

    // ---- persistent encoder (128 blocks, hierarchical barriers) -------------
    hipLaunchKernelGGL(enc_persist, dim3(128), dim3(256), 0, stream,
                       WhhFg, WhhRg, preAF, preAR, enc_b_f, enc_b_r, x_mask,
                       hAbuf, hBbuf, ctxB, encSync);

    // ---- G = ctx @ Wz_ctx^T  (overwrites dead preA region) ------------------
    mg<1, 0, 0>(stream, dim3(64, 48, 1), ctxB, 1024, WzB, 2560, nullptr, nullptr,
                G, 4096, 1024);

    // ---- init states + attention precomputes -------------------------------
    hipLaunchKernelGGL(ctx_mean_k, dim3(64), dim3(256), 0, stream, ctxB, x_mask, cmB);
    mg<1, 1, 0>(stream, dim3(16, 1, 1), cmB, 1024, h0WB, 1024, h0_b, nullptr, htR, 1024, 1024);
    mg<0, 1, 0>(stream, dim3(16, 1, 1), cmB, 1024, c0WB, 1024, c0_b, nullptr, ctF, 1024, 1024);
    mg<1, 0, 0>(stream, dim3(8, 48, 1), ctxB, 1024, W1cB, 1024, att1_b, nullptr, attctxB, 512, 1024);
    mg<1, 0, 0>(stream, dim3(8, 48, 1), yembB, 512, W1yB, 512, nullptr, nullptr, preYB, 512, 512);

    // ---- persistent decoder (256 blocks x 512 threads) ----------------------
    hipLaunchKernelGGL(dec_persist, dim3(256), dim3(512), 0, stream,
                       WzB, W1hB, attctxB, ctxB, preYB, yembB, att2_W, att2_b,
                       x_mask, cell_b, htR, ctF, svB, alphaB, G, c3r, decFlags, decGo);

    // ---- batched tail (part/rB/rmaxB alias dead G) --------------------------
    mg<1, 0, 0>(stream, dim3(16, 48, 1), c3r, 2560, readWB, 2560, read_b, nullptr, rB, 1024, 2560);
    hipLaunchKernelGGL(maxpair, dim3(6144), dim3(256), 0, stream, rB, rmaxB);
    hipLaunchKernelGGL(logits_lsm, dim3(48, 500), dim3(256), 0, stream,
                       rmaxB, outWB, out_b, y_data, part, logy);
    hipLaunchKernelGGL(lsm_reduce, dim3(3072), dim3(64), 0, stream, part, logy, y_mask, lossb);
    hipLaunchKernelGGL(final_sum, dim3(1), dim3(256), 0, stream, lossb, out);
}

// Round 16
// 2770.366 us; speedup vs baseline: 1.5710x; 1.1442x over previous
//
#include <hip/hip_runtime.h>
#include <hip/hip_bf16.h>
#include <math.h>

// Tx=48 Ty=48 Bn=64 DW=512 E=512 D=1024 A=512 VS=VT=32000
typedef __attribute__((ext_vector_type(8))) short bf16x8;
typedef __attribute__((ext_vector_type(4))) short bf16x4;
typedef __attribute__((ext_vector_type(4))) float f32x4;
typedef unsigned short u16;
typedef unsigned int u32;

__device__ __forceinline__ float bf2f(u16 u) {
    union { float f; u32 i; } v; v.i = ((u32)u) << 16; return v.f;
}
__device__ __forceinline__ float bflo(u32 v) {
    union { float f; u32 u; } x; x.u = v << 16; return x.f;
}
__device__ __forceinline__ float bfhi(u32 v) {
    union { float f; u32 u; } x; x.u = v & 0xFFFF0000u; return x.f;
}
__device__ __forceinline__ u16 f2bf(float x) {
    union { float f; u32 u; } v; v.f = x;
    u32 r = v.u + 0x7FFF + ((v.u >> 16) & 1);
    return (u16)(r >> 16);
}
__device__ __forceinline__ u32 f2bf2(float a, float b) {
    return (u32)f2bf(a) | ((u32)f2bf(b) << 16);
}
__device__ __forceinline__ float sigf(float x) { return 1.0f / (1.0f + expf(-x)); }

// Write-through stores to the memory-side (L3) coherence point.
__device__ __forceinline__ void st_wt_u16(u16* p, u16 v) {
    asm volatile("global_store_short %0, %1, off sc0 sc1" :: "v"(p), "v"((u32)v) : "memory");
}
__device__ __forceinline__ void st_wt_f32(float* p, float v) {
    asm volatile("global_store_dword %0, %1, off sc0 sc1" :: "v"(p), "v"(v) : "memory");
}
__device__ __forceinline__ void st_wt_u32(u32* p, u32 v) {
    asm volatile("global_store_dword %0, %1, off sc0 sc1" :: "v"(p), "v"(v) : "memory");
}

// Hierarchical barrier (R15): per-block wt flag, aggregator poll, replicated go.
__device__ __forceinline__ void gbarH(u32* flags, u32* go, int myidx, int aggbid,
                                      u32 ph, int nblk, int nrepmask) {
    __syncthreads();
    if ((int)blockIdx.x == aggbid) {
        if (threadIdx.x == 0) st_wt_u32(flags + (size_t)myidx * 16, ph);
        if (threadIdx.x < 64) {
            bool ok = false;
            if (nblk == 256) {
                const u32* p = flags + (size_t)threadIdx.x * 64;
                while (!ok) {
                    u32 a, b, c, d;
                    asm volatile(
                        "global_load_dword %0, %4, off sc0 sc1\n\t"
                        "global_load_dword %1, %5, off sc0 sc1\n\t"
                        "global_load_dword %2, %6, off sc0 sc1\n\t"
                        "global_load_dword %3, %7, off sc0 sc1\n\t"
                        "s_waitcnt vmcnt(0)"
                        : "=&v"(a), "=&v"(b), "=&v"(c), "=&v"(d)
                        : "v"(p), "v"(p + 16), "v"(p + 32), "v"(p + 48)
                        : "memory");
                    ok = __all((a >= ph) && (b >= ph) && (c >= ph) && (d >= ph));
                }
            } else {
                const u32* p = flags + (size_t)threadIdx.x * 16;
                while (!ok) {
                    u32 a;
                    asm volatile("global_load_dword %0, %1, off sc0 sc1\n\ts_waitcnt vmcnt(0)"
                                 : "=&v"(a) : "v"(p) : "memory");
                    ok = __all(a >= ph);
                }
            }
            if ((int)threadIdx.x <= nrepmask)
                st_wt_u32(go + (size_t)threadIdx.x * 16, ph);
        }
        __syncthreads();
    } else {
        if (threadIdx.x == 0) {
            st_wt_u32(flags + (size_t)myidx * 16, ph);
            const u32* gp = go + (size_t)(myidx & nrepmask) * 16;
            u32 v;
            do {
                asm volatile("global_load_dword %0, %1, off sc0 sc1\n\ts_waitcnt vmcnt(0)"
                             : "=&v"(v) : "v"(gp) : "memory");
            } while (v < ph);
        }
        __syncthreads();
    }
}

// ---------------------------------------------------------------------------
// MFMA GEMM (batched ops): C = act(A@B^T + bias + Cin), 64x64 tile.
// ---------------------------------------------------------------------------
template<int OUTBF, int ACT, int CIN>
__global__ __launch_bounds__(256) void mgemm(
    const u16* __restrict__ A, int lda,
    const u16* __restrict__ B, int ldb,
    const float* __restrict__ bias,
    const u16* __restrict__ Cin,
    void* __restrict__ Cout,
    int N, int K,
    const u16* A2, const u16* B2, const float* bias2, const u16* Cin2, void* Cout2)
{
    if (blockIdx.z == 1) { A = A2; B = B2; bias = bias2; Cin = Cin2; Cout = Cout2; }
    const int lane = threadIdx.x & 63;
    const int wave = threadIdx.x >> 6;
    const int wm = wave >> 1, wn = wave & 1;
    const int lr = lane & 15, lg = lane >> 4;
    const size_t bm = (size_t)blockIdx.y * 64, bn = (size_t)blockIdx.x * 64;
    const u16* Ap = A + (bm + wm * 32 + lr) * (size_t)lda + lg * 8;
    const u16* Bp = B + (bn + wn * 32 + lr) * (size_t)ldb + lg * 8;
    f32x4 acc[2][2] = {};
    for (int k0 = 0; k0 < K; k0 += 32) {
        bf16x8 a0 = *(const bf16x8*)(Ap + k0);
        bf16x8 a1 = *(const bf16x8*)(Ap + k0 + 16 * (size_t)lda);
        bf16x8 b0 = *(const bf16x8*)(Bp + k0);
        bf16x8 b1 = *(const bf16x8*)(Bp + k0 + 16 * (size_t)ldb);
        acc[0][0] = __builtin_amdgcn_mfma_f32_16x16x32_bf16(a0, b0, acc[0][0], 0, 0, 0);
        acc[0][1] = __builtin_amdgcn_mfma_f32_16x16x32_bf16(a0, b1, acc[0][1], 0, 0, 0);
        acc[1][0] = __builtin_amdgcn_mfma_f32_16x16x32_bf16(a1, b0, acc[1][0], 0, 0, 0);
        acc[1][1] = __builtin_amdgcn_mfma_f32_16x16x32_bf16(a1, b1, acc[1][1], 0, 0, 0);
    }
    #pragma unroll
    for (int fi = 0; fi < 2; ++fi)
    #pragma unroll
    for (int fj = 0; fj < 2; ++fj) {
        size_t col = bn + wn * 32 + fj * 16 + lr;
        float bv = bias ? bias[col] : 0.0f;
        #pragma unroll
        for (int r = 0; r < 4; ++r) {
            size_t row = bm + wm * 32 + fi * 16 + lg * 4 + r;
            float v = acc[fi][fj][r] + bv;
            if constexpr (CIN) v += bf2f(Cin[row * (size_t)N + col]);
            if constexpr (ACT) v = tanhf(v);
            if constexpr (OUTBF) ((u16*)Cout)[row * (size_t)N + col] = f2bf(v);
            else                 ((float*)Cout)[row * (size_t)N + col] = v;
        }
    }
}

// ---------------------------------------------------------------------------
// Persistent encoder (unchanged from R15): 128 blocks, 1 bar/step.
// ---------------------------------------------------------------------------
__global__ __launch_bounds__(256, 1) void enc_persist(
    const u16* __restrict__ WhhFg, const u16* __restrict__ WhhRg,
    const u16* __restrict__ preAF, const u16* __restrict__ preAR,
    const float* __restrict__ bF, const float* __restrict__ bR,
    const float* __restrict__ xm,
    u16* hAbuf, u16* hBbuf,
    u16* __restrict__ ctxB, u32* encSync)
{
    const int tid = threadIdx.x, bid = blockIdx.x;
    const int lane = tid & 63, wave = tid >> 6;
    const int lr = lane & 15, lg = lane >> 4;
    const int dir = bid >> 6;
    const int nb = bid & 63;
    const u16* Whh = dir ? WhhRg : WhhFg;
    const u16* preA = dir ? preAR : preAF;
    const float* bias = dir ? bR : bF;
    u16* hbase = dir ? hBbuf : hAbuf;
    u32* flags = encSync + (size_t)dir * 1280;
    u32* go = flags + 1024;
    const int aggbid = dir * 64;
    __shared__ u16 whh[32 * 520];
    __shared__ float zs[64 * 33];
    for (int i = tid; i < 32 * 64; i += 256) {
        int r = i >> 6, c = (i & 63) * 8;
        *(bf16x8*)&whh[r * 520 + c] = *(const bf16x8*)&Whh[(size_t)(nb * 32 + r) * 512 + c];
    }
    __syncthreads();
    const int gb = tid & 63, dl0 = tid >> 6;
    float creg[2] = {0.f, 0.f};
    u32 ph = 0;
    for (int s = 0; s < 48; ++s) {
        const int t = dir ? (47 - s) : s;
        if (s > 0) {
            const u16* hc = hbase + (size_t)s * 32768;
            const u16* Ap = hc + (wave * 16 + lr) * 512 + lg * 8;
            f32x4 acc0 = {}, acc1 = {};
            #pragma unroll 4
            for (int k0 = 0; k0 < 512; k0 += 32) {
                bf16x8 a  = *(const bf16x8*)(Ap + k0);
                bf16x8 b0 = *(const bf16x8*)&whh[lr * 520 + k0 + lg * 8];
                bf16x8 b1 = *(const bf16x8*)&whh[(16 + lr) * 520 + k0 + lg * 8];
                acc0 = __builtin_amdgcn_mfma_f32_16x16x32_bf16(a, b0, acc0, 0, 0, 0);
                acc1 = __builtin_amdgcn_mfma_f32_16x16x32_bf16(a, b1, acc1, 0, 0, 0);
            }
            #pragma unroll
            for (int r = 0; r < 4; ++r) {
                int row = wave * 16 + lg * 4 + r;
                zs[row * 33 + lr] = acc0[r];
                zs[row * 33 + 16 + lr] = acc1[r];
            }
            __syncthreads();
        }
        u16* hnx = hbase + (size_t)(s + 1) * 32768;
        #pragma unroll
        for (int q = 0; q < 2; ++q) {
            int dl = dl0 + q * 4;
            int dg = nb * 8 + dl;
            bf16x4 pa = *(const bf16x4*)&preA[((size_t)t * 64 + gb) * 2048 + nb * 32 + 4 * dl];
            float iv = bf2f((u16)pa[0]) + bias[dg];
            float fv = bf2f((u16)pa[1]) + bias[512 + dg];
            float gv = bf2f((u16)pa[2]) + bias[1024 + dg];
            float ov = bf2f((u16)pa[3]) + bias[1536 + dg];
            if (s > 0) {
                iv += zs[gb * 33 + 4 * dl + 0];
                fv += zs[gb * 33 + 4 * dl + 1];
                gv += zs[gb * 33 + 4 * dl + 2];
                ov += zs[gb * 33 + 4 * dl + 3];
            }
            float cn = sigf(fv) * creg[q] + sigf(iv) * tanhf(gv);
            float hn = sigf(ov) * tanhf(cn);
            creg[q] = cn;
            st_wt_u16(&hnx[gb * 512 + dg], f2bf(hn));
            ctxB[((size_t)t * 64 + gb) * 1024 + dir * 512 + dg] = f2bf(hn * xm[t * 64 + gb]);
        }
        if (s < 47) gbarH(flags, go, nb, aggbid, ++ph, 64, 15);
    }
}

// ---------------------------------------------------------------------------
// Persistent decoder: 256 blocks = 64 b x 4 col-quarters, 512 threads,
// 2 barriers/step. Each block REDUNDANTLY computes its own b's softmax
// (alpha never leaves the block) then z for its 1024-col quarter via
// gfrag (48 tp x 2 cols = 48 VGPRs, R13-proven budget). Gate pairs combine
// via shfl_xor(1). zpart flows through a rotating global buffer.
// Phases/step: AZ -> bar -> SVZ (sv GEMV waves0-3 || zpart MFMA waves4-7) -> bar.
// ---------------------------------------------------------------------------
__global__ __launch_bounds__(512, 1) void dec_persist(
    const u16* __restrict__ WzB, const u16* __restrict__ W1hB,
    const u16* __restrict__ attctxB, const u16* __restrict__ ctxB,
    const u16* __restrict__ preYB, const u16* __restrict__ yembB,
    const float* __restrict__ att2W, const float* __restrict__ att2b,
    const float* __restrict__ xmask, const float* __restrict__ cellb,
    u16* htR, const float* __restrict__ ctF,
    float* svB, float* zpartR, const u16* __restrict__ G,
    u16* c3r, u32* decFlags, u32* decGo)
{
    const int tid = threadIdx.x, bid = blockIdx.x;
    const int lane = tid & 63, wave = tid >> 6;
    const int lr = lane & 15, lg = lane >> 4;
    const int b = bid >> 2;                    // batch row (0..63)
    const int q = bid & 3;                     // column quarter (0..3)
    const int cb = ((bid & 7) << 5) | (bid >> 3);  // zpart 16-col strip (bijective)
    __shared__ u16 big[48 * 512];      // attctx rows for own b
    __shared__ u16 wzl[16 * 1544];     // Wz_yh strip for cb
    __shared__ u16 w1h[2 * 1024];
    __shared__ float scr[8352];        // SVZ: sv transpose (4x2080) | AZ: ctx partials
    __shared__ float a2s[64];

    // ---- one-time staging ----
    for (int i = tid; i < 48 * 64; i += 512) {
        int tp = i >> 6, c = (i & 63) * 8;
        *(bf16x8*)&big[tp * 512 + c] =
            *(const bf16x8*)&attctxB[((size_t)tp * 64 + b) * 512 + c];
    }
    for (int i = tid; i < 16 * 192; i += 512) {
        int r = i / 192, c = (i % 192) * 8;
        *(bf16x8*)&wzl[r * 1544 + c] =
            *(const bf16x8*)&WzB[(size_t)(cb * 16 + r) * 2560 + 1024 + c];
    }
    for (int i = tid; i < 256; i += 512) {
        int r = i >> 7, c = (i & 127) * 8;
        *(bf16x8*)&w1h[r * 1024 + c] = *(const bf16x8*)&W1hB[(size_t)(bid * 2 + r) * 1024 + c];
    }
    float a2wreg[8];
    #pragma unroll
    for (int k = 0; k < 8; ++k) a2wreg[k] = att2W[k * 64 + lane];
    float xmr = (tid < 64) ? xmask[tid * 64 + b] : 0.f;
    // ---- hoist G fragment: 2 z-cols x 48 tp = 48 u32 regs ----
    const int n0 = q * 1024 + 2 * tid;         // this thread's 2 z-columns
    u32 gfrag[48];
    #pragma unroll
    for (int tp = 0; tp < 48; ++tp)
        gfrag[tp] = *(const u32*)&G[((size_t)tp * 64 + b) * 4096 + n0];
    const int d = n0 >> 2;                     // gate group
    const int glo = (tid & 1) ? 2 : 0;         // even: gates i,f; odd: g,o
    const float cb0 = cellb[glo * 1024 + d];
    const float cb1 = cellb[(glo + 1) * 1024 + d];
    float ct_reg = (tid & 1) ? 0.f : ctF[b * 1024 + d];
    __syncthreads();
    const float att2b0 = att2b[0];

    // SVZ: sv GEMV (waves 0-3) || zpart MFMA -> zpartR (waves 4-7)
    auto svz_phase = [&](int tt) {
        const u16* htT = htR + (size_t)tt * 65536;
        if (wave < 4) {
            const int jl = wave & 1;
            const int bh = wave >> 1;
            const int j = bid * 2 + jl;
            float* svT = svB + (size_t)tt * 32768;
            bf16x8 wv0 = *(const bf16x8*)&w1h[jl * 1024 + lane * 8];
            bf16x8 wv1 = *(const bf16x8*)&w1h[jl * 1024 + 512 + lane * 8];
            float s[32];
            #pragma unroll 8
            for (int bi = 0; bi < 32; ++bi) {
                const u16* hp = htT + (bh * 32 + bi) * 1024 + lane * 8;
                bf16x8 h0 = *(const bf16x8*)(hp);
                bf16x8 h1 = *(const bf16x8*)(hp + 512);
                float a = 0.f;
                #pragma unroll
                for (int u = 0; u < 8; ++u)
                    a += bf2f((u16)h0[u]) * bf2f((u16)wv0[u])
                       + bf2f((u16)h1[u]) * bf2f((u16)wv1[u]);
                s[bi] = a;
            }
            float* zone = scr + wave * 2080;
            #pragma unroll 8
            for (int bi = 0; bi < 32; ++bi) zone[bi * 65 + lane] = s[bi];
            if (lane < 32) {
                const float* zr = zone + lane * 65;
                float tsum = 0.f;
                #pragma unroll
                for (int u = 0; u < 64; ++u) tsum += zr[u];
                int bb = bh * 32 + lane;
                st_wt_f32(&svT[bb * 512 + j],
                          tsum + bf2f(preYB[((size_t)tt * 64 + bb) * 512 + j]));
            }
        } else {
            const int bt = wave - 4;
            const u16* Ah = htT + (bt * 16 + lr) * 1024 + lg * 8;
            const u16* Ay = yembB + ((size_t)tt * 64 + bt * 16 + lr) * 512 + lg * 8;
            const u16* Bp = &wzl[lr * 1544 + lg * 8];
            f32x4 acc = {};
            #pragma unroll 4
            for (int k0 = 0; k0 < 1024; k0 += 32) {
                bf16x8 a = *(const bf16x8*)(Ah + k0);
                bf16x8 bw = *(const bf16x8*)(Bp + k0);
                acc = __builtin_amdgcn_mfma_f32_16x16x32_bf16(a, bw, acc, 0, 0, 0);
            }
            #pragma unroll 4
            for (int k0 = 0; k0 < 512; k0 += 32) {
                bf16x8 a = *(const bf16x8*)(Ay + k0);
                bf16x8 bw = *(const bf16x8*)(Bp + 1024 + k0);
                acc = __builtin_amdgcn_mfma_f32_16x16x32_bf16(a, bw, acc, 0, 0, 0);
            }
            float* zpT = zpartR + (size_t)tt * 262144;
            #pragma unroll
            for (int r = 0; r < 4; ++r) {
                int bb = bt * 16 + lg * 4 + r;
                st_wt_f32(&zpT[(size_t)bb * 4096 + cb * 16 + lr], acc[r]);
            }
        }
    };

    u32 ph = 0;
    svz_phase(0);
    gbarH(decFlags, decGo, bid, 255, ++ph, 256, 31);

    for (int t = 0; t < 48; ++t) {
        // ================= AZ phase (all blocks) =================
        {
            const float* svT = svB + (size_t)t * 32768;
            float svr[8];
            #pragma unroll
            for (int k = 0; k < 8; ++k) svr[k] = svT[b * 512 + k * 64 + lane];
            for (int tp = wave; tp < 48; tp += 8) {
                float s = 0.f;
                #pragma unroll
                for (int k = 0; k < 8; ++k)
                    s += a2wreg[k] * tanhf(bf2f(big[tp * 512 + k * 64 + lane]) + svr[k]);
                #pragma unroll
                for (int m = 32; m; m >>= 1) s += __shfl_xor(s, m);
                if (lane == 0) a2s[tp] = s + att2b0;
            }
            __syncthreads();
            if (tid < 64) {
                float v = (tid < 48) ? a2s[tid] : -1e30f;
                float m = v;
                #pragma unroll
                for (int sh = 32; sh; sh >>= 1) m = fmaxf(m, __shfl_xor(m, sh));
                float e = (tid < 48) ? expf(v - m) * xmr : 0.f;
                float ssum = e;
                #pragma unroll
                for (int sh = 32; sh; sh >>= 1) ssum += __shfl_xor(ssum, sh);
                if (tid < 48) a2s[tid] = e / (ssum + 1e-15f);
            }
            __syncthreads();
            // zpart read (early)
            float2 zp2 = *(const float2*)&zpartR[(size_t)t * 262144 + (size_t)b * 4096 + n0];
            // z accumulation over register G fragment
            float z0 = cb0 + zp2.x, z1 = cb1 + zp2.y;
            #pragma unroll
            for (int tp = 0; tp < 48; ++tp) {
                float al = a2s[tp];
                u32 g = gfrag[tp];
                z0 += al * bflo(g); z1 += al * bfhi(g);
            }
            // ctx_t partials for own 256-col quarter (tp split over 4 groups)
            {
                int gg = tid >> 7, cp = tid & 127;
                float c0 = 0.f, c1 = 0.f;
                #pragma unroll
                for (int u = 0; u < 12; ++u) {
                    int tp = gg * 12 + u;
                    float al = a2s[tp];
                    u32 cv = *(const u32*)&ctxB[((size_t)tp * 64 + b) * 1024 + q * 256 + 2 * cp];
                    c0 += al * bflo(cv); c1 += al * bfhi(cv);
                }
                scr[(gg * 128 + cp) * 2]     = c0;
                scr[(gg * 128 + cp) * 2 + 1] = c1;
            }
            __syncthreads();
            u16* c3rt = c3r + (size_t)t * 64 * 2560 + (size_t)b * 2560;
            if (tid < 128) {
                float c0 = scr[tid * 2]     + scr[(128 + tid) * 2]
                         + scr[(256 + tid) * 2] + scr[(384 + tid) * 2];
                float c1 = scr[tid * 2 + 1]     + scr[(128 + tid) * 2 + 1]
                         + scr[(256 + tid) * 2 + 1] + scr[(384 + tid) * 2 + 1];
                *(u32*)&c3rt[q * 256 + 2 * tid] = f2bf2(c0, c1);
            } else if (tid < 192) {
                int i = tid - 128;
                *(u32*)&c3rt[2048 + q * 128 + 2 * i] =
                    *(const u32*)&yembB[((size_t)t * 64 + b) * 512 + q * 128 + 2 * i];
            }
            // gates: pair exchange (even holds i,f; odd holds g,o)
            float zg = __shfl_xor(z0, 1);
            float zo = __shfl_xor(z1, 1);
            if (!(tid & 1)) {
                float cn = sigf(z1) * ct_reg + sigf(z0) * tanhf(zg);
                float hn = sigf(zo) * tanhf(cn);
                ct_reg = cn;
                u16 hb = f2bf(hn);
                st_wt_u16(&htR[(size_t)(t + 1) * 65536 + b * 1024 + d], hb);
                c3rt[1024 + d] = hb;
            }
        }
        if (t < 47) {
            gbarH(decFlags, decGo, bid, 255, ++ph, 256, 31);
            svz_phase(t + 1);
            gbarH(decFlags, decGo, bid, 255, ++ph, 256, 31);
        }
    }
}

// ---------------------------------------------------------------------------
// Fused logits GEMM + partial log-softmax. Grid (48, 500).
// ---------------------------------------------------------------------------
__global__ __launch_bounds__(256) void logits_lsm(
    const u16* __restrict__ A, const u16* __restrict__ B,
    const float* __restrict__ outb, const int* __restrict__ ydata,
    float2* __restrict__ part, float* __restrict__ logy)
{
    const int lane = threadIdx.x & 63;
    const int wave = threadIdx.x >> 6;
    const int wm = wave >> 1, wn = wave & 1;
    const int lr = lane & 15, lg = lane >> 4;
    const size_t bm = (size_t)blockIdx.x * 64, bn = (size_t)blockIdx.y * 64;
    const u16* Ap = A + (bm + wm * 32 + lr) * 512 + lg * 8;
    const u16* Bp = B + (bn + wn * 32 + lr) * 512 + lg * 8;
    f32x4 acc[2][2] = {};
    for (int k0 = 0; k0 < 512; k0 += 32) {
        bf16x8 a0 = *(const bf16x8*)(Ap + k0);
        bf16x8 a1 = *(const bf16x8*)(Ap + k0 + 16 * 512);
        bf16x8 b0 = *(const bf16x8*)(Bp + k0);
        bf16x8 b1 = *(const bf16x8*)(Bp + k0 + 16 * 512);
        acc[0][0] = __builtin_amdgcn_mfma_f32_16x16x32_bf16(a0, b0, acc[0][0], 0, 0, 0);
        acc[0][1] = __builtin_amdgcn_mfma_f32_16x16x32_bf16(a0, b1, acc[0][1], 0, 0, 0);
        acc[1][0] = __builtin_amdgcn_mfma_f32_16x16x32_bf16(a1, b0, acc[1][0], 0, 0, 0);
        acc[1][1] = __builtin_amdgcn_mfma_f32_16x16x32_bf16(a1, b1, acc[1][1], 0, 0, 0);
    }
    __shared__ float sm[64][2];
    __shared__ float ss[64][2];
    const float b0 = outb[bn + wn * 32 + lr];
    const float b1 = outb[bn + wn * 32 + 16 + lr];
    #pragma unroll
    for (int fi = 0; fi < 2; ++fi) {
        #pragma unroll
        for (int r = 0; r < 4; ++r) {
            int rloc = wm * 32 + fi * 16 + lg * 4 + r;
            size_t row = bm + rloc;
            float v0 = acc[fi][0][r] + b0;
            float v1 = acc[fi][1][r] + b1;
            int yt = ydata[row];
            if (yt == (int)(bn + wn * 32 + lr))      logy[row] = v0;
            if (yt == (int)(bn + wn * 32 + 16 + lr)) logy[row] = v1;
            float m = fmaxf(v0, v1);
            #pragma unroll
            for (int sh = 1; sh < 16; sh <<= 1) m = fmaxf(m, __shfl_xor(m, sh));
            float s = expf(v0 - m) + expf(v1 - m);
            #pragma unroll
            for (int sh = 1; sh < 16; sh <<= 1) s += __shfl_xor(s, sh);
            if (lr == 0) { sm[rloc][wn] = m; ss[rloc][wn] = s; }
        }
    }
    __syncthreads();
    if (threadIdx.x < 64) {
        float m0 = sm[threadIdx.x][0], m1 = sm[threadIdx.x][1];
        float m = fmaxf(m0, m1);
        float s = ss[threadIdx.x][0] * expf(m0 - m) + ss[threadIdx.x][1] * expf(m1 - m);
        part[(bm + threadIdx.x) * 500 + blockIdx.y] = make_float2(m, s);
    }
}

__global__ __launch_bounds__(64) void lsm_reduce(
    const float2* __restrict__ part, const float* __restrict__ logy,
    const float* __restrict__ ymask, float* __restrict__ lossb)
{
    int r = blockIdx.x, lane = threadIdx.x;
    float m = -1e30f;
    for (int i = lane; i < 500; i += 64) m = fmaxf(m, part[(size_t)r * 500 + i].x);
    #pragma unroll
    for (int sh = 32; sh; sh >>= 1) m = fmaxf(m, __shfl_xor(m, sh));
    float s = 0.f;
    for (int i = lane; i < 500; i += 64) {
        float2 p = part[(size_t)r * 500 + i];
        s += p.y * expf(p.x - m);
    }
    #pragma unroll
    for (int sh = 32; sh; sh >>= 1) s += __shfl_xor(s, sh);
    if (lane == 0) {
        float lp = logy[r] - m - logf(s);
        lossb[r] = -lp * ymask[r] * (1.0f / 64.0f);
    }
}

// ---------------------------------------------------------------------------
// Small kernels
// ---------------------------------------------------------------------------
__global__ void convb(const float* __restrict__ src, int sld, int K,
                      u16* __restrict__ dst, int total)
{
    int idx = blockIdx.x * 256 + threadIdx.x;
    if (idx >= total) return;
    int n = idx / K, k = idx - n * K;
    dst[idx] = f2bf(src[(size_t)n * sld + k]);
}

__global__ void conv_gate4(const float* __restrict__ src, u16* __restrict__ dst,
                           int H, int K, int total)
{
    int idx = blockIdx.x * 256 + threadIdx.x;
    if (idx >= total) return;
    int n = idx / K, k = idx - n * K;
    int d = n >> 2, g = n & 3;
    dst[idx] = f2bf(src[(size_t)(g * H + d) * K + k]);
}

__global__ void build_wz_g4(const float* __restrict__ Wih, const float* __restrict__ Whh,
                            u16* __restrict__ Wz)
{
    int idx = blockIdx.x * 256 + threadIdx.x;  // 4096*2560
    int j = idx % 2560, np = idx / 2560;
    int n = (np & 3) * 1024 + (np >> 2);
    float v;
    if (j < 1024)      v = Wih[(size_t)n * 1536 + 512 + j];
    else if (j < 2048) v = Whh[(size_t)n * 1024 + (j - 1024)];
    else               v = Wih[(size_t)n * 1536 + (j - 2048)];
    Wz[idx] = f2bf(v);
}

__global__ void embed_kernel(const int* __restrict__ xd, const float* __restrict__ xm,
                             const int* __restrict__ yd,
                             const float* __restrict__ src_emb, const float* __restrict__ dec_emb,
                             u16* __restrict__ x_emb, u16* __restrict__ y_emb)
{
    int idx = blockIdx.x * 256 + threadIdx.x;   // 48*64*512
    int d = idx & 511;
    int tb = idx >> 9;
    if (blockIdx.y == 0) {
        int v = xd[tb];
        x_emb[idx] = f2bf(src_emb[(size_t)v * 512 + d] * xm[tb]);
    } else {
        int t = tb >> 6, b = tb & 63;
        int v = (t == 0) ? 0 : yd[(t - 1) * 64 + b];
        y_emb[idx] = f2bf(dec_emb[(size_t)v * 512 + d]);
    }
}

__global__ __launch_bounds__(256) void ctx_mean_k(const u16* __restrict__ ctxB,
                                                  const float* __restrict__ xm,
                                                  u16* __restrict__ cm)
{
    int b = blockIdx.x, tid = threadIdx.x;
    float msum = 0.f;
    for (int t = 0; t < 48; ++t) msum += xm[t * 64 + b];
    float inv = 1.0f / msum;
    for (int e = tid; e < 1024; e += 256) {
        float s = 0.f;
        for (int t = 0; t < 48; ++t)
            s += bf2f(ctxB[(size_t)(t * 64 + b) * 1024 + e]) * xm[t * 64 + b];
        cm[b * 1024 + e] = f2bf(s * inv);
    }
}

__global__ void maxpair(const u16* __restrict__ rB, u16* __restrict__ rmax)
{
    int idx = blockIdx.x * 256 + threadIdx.x;   // 3072*512
    int row = idx >> 9, d = idx & 511;
    float a = bf2f(rB[(size_t)row * 1024 + 2 * d]);
    float b = bf2f(rB[(size_t)row * 1024 + 2 * d + 1]);
    rmax[idx] = f2bf(fmaxf(a, b));
}

__global__ __launch_bounds__(256) void final_sum(const float* __restrict__ lossb,
                                                 float* __restrict__ out)
{
    __shared__ float red[4];
    int tid = threadIdx.x;
    float s = 0.f;
    for (int i = tid; i < 3072; i += 256) s += lossb[i];
    for (int sh = 32; sh; sh >>= 1) s += __shfl_xor(s, sh);
    if ((tid & 63) == 0) red[tid >> 6] = s;
    __syncthreads();
    if (tid == 0) out[0] = red[0] + red[1] + red[2] + red[3];
}

// ---------------------------------------------------------------------------
// Host
// ---------------------------------------------------------------------------
template<int OUTBF, int ACT, int CIN>
static void mg(hipStream_t st, dim3 grid,
               const u16* A, int lda, const u16* B, int ldb,
               const float* bias, const u16* Cin, void* C, int N, int K,
               const u16* A2 = nullptr, const u16* B2 = nullptr,
               const float* bias2 = nullptr, const u16* Cin2 = nullptr, void* C2 = nullptr)
{
    hipLaunchKernelGGL((mgemm<OUTBF, ACT, CIN>), grid, dim3(256), 0, st,
                       A, lda, B, ldb, bias, Cin, C, N, K, A2, B2, bias2, Cin2, C2);
}

extern "C" void kernel_launch(void* const* d_in, const int* in_sizes, int n_in,
                              void* d_out, int out_size, void* d_ws, size_t ws_size,
                              hipStream_t stream)
{
    const int*   x_data    = (const int*)d_in[0];
    const float* x_mask    = (const float*)d_in[1];
    const int*   y_data    = (const int*)d_in[2];
    const float* y_mask    = (const float*)d_in[3];
    const float* src_emb   = (const float*)d_in[4];
    const float* dec_emb   = (const float*)d_in[5];
    const float* enc_Wih_f = (const float*)d_in[6];
    const float* enc_Whh_f = (const float*)d_in[7];
    const float* enc_b_f   = (const float*)d_in[8];
    const float* enc_Wih_r = (const float*)d_in[9];
    const float* enc_Whh_r = (const float*)d_in[10];
    const float* enc_b_r   = (const float*)d_in[11];
    const float* h0_W      = (const float*)d_in[12];
    const float* h0_b      = (const float*)d_in[13];
    const float* c0_W      = (const float*)d_in[14];
    const float* c0_b      = (const float*)d_in[15];
    const float* att1_W    = (const float*)d_in[16];
    const float* att1_b    = (const float*)d_in[17];
    const float* att2_W    = (const float*)d_in[18];
    const float* att2_b    = (const float*)d_in[19];
    const float* cell_Wih  = (const float*)d_in[20];
    const float* cell_Whh  = (const float*)d_in[21];
    const float* cell_b    = (const float*)d_in[22];
    const float* read_W    = (const float*)d_in[23];
    const float* read_b    = (const float*)d_in[24];
    const float* out_W     = (const float*)d_in[25];
    const float* out_b     = (const float*)d_in[26];
    float* out = (float*)d_out;
    (void)in_sizes; (void)n_in; (void)out_size; (void)ws_size;

    char* base = (char*)d_ws;
    size_t off = 0;
    auto ab = [&](size_t bytes) -> void* {
        void* p = base + off;
        off += (bytes + 255) & ~(size_t)255;
        return p;
    };
    u16* WzB     = (u16*)ab(4096UL * 2560 * 2);
    u16* outWB   = (u16*)ab(32000UL * 512 * 2);
    u16* readWB  = (u16*)ab(1024UL * 2560 * 2);
    u16* WihFg   = (u16*)ab(2048UL * 512 * 2);
    u16* WihRg   = (u16*)ab(2048UL * 512 * 2);
    u16* WhhFg   = (u16*)ab(2048UL * 512 * 2);
    u16* WhhRg   = (u16*)ab(2048UL * 512 * 2);
    u16* h0WB    = (u16*)ab(1024UL * 1024 * 2);
    u16* c0WB    = (u16*)ab(1024UL * 1024 * 2);
    u16* W1cB    = (u16*)ab(512UL * 1024 * 2);
    u16* W1yB    = (u16*)ab(512UL * 512 * 2);
    u16* W1hB    = (u16*)ab(512UL * 1024 * 2);
    u16* xembB   = (u16*)ab(3072UL * 512 * 2);
    u16* yembB   = (u16*)ab(3072UL * 512 * 2);
    u16* preAF   = (u16*)ab(3072UL * 2048 * 2);   // dead after encoder
    u16* preAR   = (u16*)ab(3072UL * 2048 * 2);   // dead after encoder
    // G (25.17 MB) aliases preAF+preAR exactly (computed after encoder).
    u16* G       = preAF;
    // Tail buffers alias G (dead after decoder): part | rB | rmaxB
    float2* part = (float2*)preAF;                             // 12,288,000 B
    u16* rB      = (u16*)((char*)preAF + 12288000);            //  6,291,456 B
    u16* rmaxB   = (u16*)((char*)preAF + 12288000 + 6291456);  //  3,145,728 B
    u16* ctxB    = (u16*)ab(3072UL * 1024 * 2);
    u16* attctxB = (u16*)ab(3072UL * 512 * 2);
    u16* preYB   = (u16*)ab(3072UL * 512 * 2);
    u16* cmB     = (u16*)ab(64UL * 1024 * 2);
    u16* hAbuf   = (u16*)ab(49UL * 64 * 512 * 2);   // encoder fwd h rotation
    u16* hBbuf   = (u16*)ab(49UL * 64 * 512 * 2);   // encoder rev h rotation
    u16* htR     = (u16*)ab(49UL * 64 * 1024 * 2);  // decoder ht rotation
    float* ctF   = (float*)ab(64UL * 1024 * 4);
    float* svB   = (float*)ab(48UL * 64 * 512 * 4); // sv rotation
    float* zpartR= (float*)ab(48UL * 64 * 4096 * 4);// zpart rotation (48 MB)
    u16* c3r     = (u16*)ab(3072UL * 2560 * 2);
    float* logy  = (float*)ab(3072UL * 4);
    float* lossb = (float*)ab(3072UL * 4);
    u32* sync    = (u32*)ab(32768);
    u32* decFlags = sync;                 // 256 flags x 16 u32 (64B lines)
    u32* decGo    = sync + 4096;          // 32 replicas x 16 u32
    u32* encSync  = sync + 4608;          // 2 dirs x (64 flags + 16 go) x 16 u32

    // ---- setup ------------------------------------------------------------
    hipMemsetAsync(sync, 0, 32768, stream);
    hipMemsetAsync(hAbuf, 0, 64UL * 512 * 2, stream);   // h_0 fwd = 0
    hipMemsetAsync(hBbuf, 0, 64UL * 512 * 2, stream);   // h_0 rev = 0
    hipLaunchKernelGGL(build_wz_g4, dim3(40960), dim3(256), 0, stream, cell_Wih, cell_Whh, WzB);
    auto conv = [&](const float* src, int sld, int K, u16* dst, size_t total) {
        hipLaunchKernelGGL(convb, dim3((unsigned)((total + 255) / 256)), dim3(256), 0, stream,
                           src, sld, K, dst, (int)total);
    };
    auto convg = [&](const float* src, u16* dst, int H, int K) {
        size_t total = (size_t)4 * H * K;
        hipLaunchKernelGGL(conv_gate4, dim3((unsigned)((total + 255) / 256)), dim3(256), 0, stream,
                           src, dst, H, K, (int)total);
    };
    conv(out_W, 512, 512, outWB, 32000UL * 512);
    conv(read_W, 2560, 2560, readWB, 1024UL * 2560);
    convg(enc_Wih_f, WihFg, 512, 512);
    convg(enc_Wih_r, WihRg, 512, 512);
    convg(enc_Whh_f, WhhFg, 512, 512);
    convg(enc_Whh_r, WhhRg, 512, 512);
    conv(h0_W, 1024, 1024, h0WB, 1024UL * 1024);
    conv(c0_W, 1024, 1024, c0WB, 1024UL * 1024);
    conv(att1_W, 2560, 1024, W1cB, 512UL * 1024);
    conv(att1_W + 1024, 2560, 512, W1yB, 512UL * 512);
    conv(att1_W + 1536, 2560, 1024, W1hB, 512UL * 1024);
    hipLaunchKernelGGL(embed_kernel, dim3(6144, 2), dim3(256), 0, stream,
                       x_data, x_mask, y_data, src_emb, dec_emb, xembB, yembB);

    // preA = x_emb @ Wih'^T (bias added in encoder gates)
    mg<1, 0, 0>(stream, dim3(32, 48, 2), xembB, 512, WihFg, 512, nullptr, nullptr,
                preAF, 2048, 512, xembB, WihRg, nullptr, nullptr, preAR);

    // ---- persistent encoder (128 blocks, hierarchical barriers) -------------
    hipLaunchKernelGGL(enc_persist, dim3(128), dim3(256), 0, stream,
                       WhhFg, WhhRg, preAF, preAR, enc_b_f, enc_b_r, x_mask,
                       hAbuf, hBbuf, ctxB, encSync);

    // ---- G = ctx @ Wz_ctx^T  (overwrites dead preA region) ------------------
    mg<1, 0, 0>(stream, dim3(64, 48, 1), ctxB, 1024, WzB, 2560, nullptr, nullptr,
                G, 4096, 1024);

    // ---- init states + attention precomputes -------------------------------
    hipLaunchKernelGGL(ctx_mean_k, dim3(64), dim3(256), 0, stream, ctxB, x_mask, cmB);
    mg<1, 1, 0>(stream, dim3(16, 1, 1), cmB, 1024, h0WB, 1024, h0_b, nullptr, htR, 1024, 1024);
    mg<0, 1, 0>(stream, dim3(16, 1, 1), cmB, 1024, c0WB, 1024, c0_b, nullptr, ctF, 1024, 1024);
    mg<1, 0, 0>(stream, dim3(8, 48, 1), ctxB, 1024, W1cB, 1024, att1_b, nullptr, attctxB, 512, 1024);
    mg<1, 0, 0>(stream, dim3(8, 48, 1), yembB, 512, W1yB, 512, nullptr, nullptr, preYB, 512, 512);

    // ---- persistent decoder (256 blocks x 512 threads, 2 bars/step) ---------
    hipLaunchKernelGGL(dec_persist, dim3(256), dim3(512), 0, stream,
                       WzB, W1hB, attctxB, ctxB, preYB, yembB, att2_W, att2_b,
                       x_mask, cell_b, htR, ctF, svB, zpartR, G, c3r, decFlags, decGo);

    // ---- batched tail (part/rB/rmaxB alias dead G) --------------------------
    mg<1, 0, 0>(stream, dim3(16, 48, 1), c3r, 2560, readWB, 2560, read_b, nullptr, rB, 1024, 2560);
    hipLaunchKernelGGL(maxpair, dim3(6144), dim3(256), 0, stream, rB, rmaxB);
    hipLaunchKernelGGL(logits_lsm, dim3(48, 500), dim3(256), 0, stream,
                       rmaxB, outWB, out_b, y_data, part, logy);
    hipLaunchKernelGGL(lsm_reduce, dim3(3072), dim3(64), 0, stream, part, logy, y_mask, lossb);
    hipLaunchKernelGGL(final_sum, dim3(1), dim3(256), 0, stream, lossb, out);
}